// Round 1
// baseline (4849.703 us; speedup 1.0000x reference)
//
#include <hip/hip_runtime.h>
#include <math.h>

// Projector MPS chain, N=256, S=2, D=64, d=2, B=64, NOUT=129, NIN=127.
// Kernel 1: blocks 0..63 -> per-batch <psi|psi> chain -> ws[b]
//           block 64     -> _log_norm chain           -> ws[64]
// Kernel 2: out[b] = ws[b] - ws[64]

#define PADB 66   // batch-path LDS plane stride
#define ALS  68   // lognorm Al stride (float4-aligned rows)
#define MS   260  // lognorm M stride (1040 B rows, float4-aligned)
#define TS   257  // lognorm Tr stride (scalar access, 2-way-conflict-free)
// batch path: 6*64*66 = 25344 + 128 (A0s) + 4 (red) = 25476 floats
// lognorm:    64*68 + 64*260 + 64*257 = 37440 + 4 (red) = 37444 floats
#define SMEM_FLOATS 37456

__device__ __forceinline__ float blk_max(float v, float* red, int tid) {
#pragma unroll
    for (int off = 32; off > 0; off >>= 1)
        v = fmaxf(v, __shfl_xor(v, off, 64));
    __syncthreads();                 // protect red reuse
    if ((tid & 63) == 0) red[tid >> 6] = v;
    __syncthreads();
    return fmaxf(fmaxf(red[0], red[1]), fmaxf(red[2], red[3]));
}

// One _log_norm site: Al <- sum_{ij} M_ij^T Al M_ij   (Al assumed pre-normalized)
// QW = d*d = 4 for output sites, d = 2 for input sites.
template <int QW>
__device__ __forceinline__ void lognorm_site(const float* __restrict__ Mg,
                                             float* Al, float* M, float* Tr,
                                             int tid) {
    const int tx = tid & 15, ty = tid >> 4;
    const int rowlen = 64 * QW;
    // stage M (row-major [64][rowlen]) into LDS, padded rows
    for (int f = tid; f < 16 * rowlen; f += 256) {
        float4 m4 = *reinterpret_cast<const float4*>(Mg + 4 * f);
        int dd = (4 * f) / rowlen;
        int cc = (4 * f) % rowlen;
        *reinterpret_cast<float4*>(M + dd * MS + cc) = m4;
    }
    __syncthreads();  // M ready (normalized Al also ordered by this barrier)

    // stage1: Tr[k][u*QW+ij] = sum_d M[d][k*QW+ij] * Al[d][u]
    float t[4][4 * QW];
#pragma unroll
    for (int a = 0; a < 4; a++)
#pragma unroll
        for (int c = 0; c < 4 * QW; c++) t[a][c] = 0.0f;
    for (int dd = 0; dd < 64; dd++) {
        float4 alv4 = *reinterpret_cast<const float4*>(Al + dd * ALS + 4 * tx);
        float alv[4] = {alv4.x, alv4.y, alv4.z, alv4.w};
        float mv[4][QW];
#pragma unroll
        for (int kk = 0; kk < 4; kk++) {
            if constexpr (QW == 4) {
                float4 q = *reinterpret_cast<const float4*>(M + dd * MS + (4 * ty + kk) * 4);
                mv[kk][0] = q.x; mv[kk][1] = q.y; mv[kk][2] = q.z; mv[kk][3] = q.w;
            } else {
                float2 q = *reinterpret_cast<const float2*>(M + dd * MS + (4 * ty + kk) * 2);
                mv[kk][0] = q.x; mv[kk][1] = q.y;
            }
        }
#pragma unroll
        for (int kk = 0; kk < 4; kk++)
#pragma unroll
            for (int uu = 0; uu < 4; uu++)
#pragma unroll
                for (int ij = 0; ij < QW; ij++)
                    t[kk][uu * QW + ij] += mv[kk][ij] * alv[uu];
    }
#pragma unroll
    for (int kk = 0; kk < 4; kk++)
#pragma unroll
        for (int c = 0; c < 4 * QW; c++)
            Tr[(4 * ty + kk) * TS + 4 * QW * tx + c] = t[kk][c];
    __syncthreads();  // Tr ready; all stage1 Al reads complete

    // stage2: Al[k][l] = sum_{u,ij} Tr[k][u*QW+ij] * M[u][l*QW+ij]
    float acc[16];
#pragma unroll
    for (int a = 0; a < 16; a++) acc[a] = 0.0f;
    for (int u = 0; u < 64; u++) {
        float mrow[4][QW];
        if constexpr (QW == 4) {
#pragma unroll
            for (int ll = 0; ll < 4; ll++) {
                float4 q = *reinterpret_cast<const float4*>(M + u * MS + 16 * tx + 4 * ll);
                mrow[ll][0] = q.x; mrow[ll][1] = q.y; mrow[ll][2] = q.z; mrow[ll][3] = q.w;
            }
        } else {
#pragma unroll
            for (int ll = 0; ll < 4; ll += 2) {
                float4 q = *reinterpret_cast<const float4*>(M + u * MS + 8 * tx + 2 * ll);
                mrow[ll][0] = q.x; mrow[ll][1] = q.y;
                mrow[ll + 1][0] = q.z; mrow[ll + 1][1] = q.w;
            }
        }
#pragma unroll
        for (int ij = 0; ij < QW; ij++) {
            float tv[4];
#pragma unroll
            for (int kk = 0; kk < 4; kk++)
                tv[kk] = Tr[(4 * ty + kk) * TS + u * QW + ij];
#pragma unroll
            for (int kk = 0; kk < 4; kk++)
#pragma unroll
                for (int ll = 0; ll < 4; ll++)
                    acc[kk * 4 + ll] += tv[kk] * mrow[ll][ij];
        }
    }
#pragma unroll
    for (int kk = 0; kk < 4; kk++)
#pragma unroll
        for (int ll = 0; ll < 4; ll++)
            Al[(4 * ty + kk) * ALS + 4 * tx + ll] = acc[kk * 4 + ll];
    // caller barriers (loop-top) before Al is re-read
}

__global__ __launch_bounds__(256) void proj_chain(
    const float* __restrict__ inp,      // [256][64][2]
    const float* __restrict__ mps_in,   // [127][64][64][2]
    const float* __restrict__ mps_out,  // [129][64][64][2][2]
    float* __restrict__ ws)             // [65]
{
    __shared__ __align__(16) float smem[SMEM_FLOATS];
    const int tid = threadIdx.x;

    if (blockIdx.x == 64) {
        // ---------------- _log_norm chain ----------------
        float* Al = smem;                 // [64][68]
        float* M  = smem + 64 * ALS;      // [64][260]
        float* Tr = M + 64 * MS;          // [64][257]
        float* red = Tr + 64 * TS;        // [4]
        float accl = 0.0f;
#pragma unroll
        for (int n = 0; n < 16; n++) {
            int e = tid + 256 * n;
            Al[(e >> 6) * ALS + (e & 63)] = (e == 0) ? 1.0f : 0.0f;
        }
        int i_in = 0;
        for (int i = 0; i < 256; i++) {
            __syncthreads();  // Al from previous stage2 visible; M/Tr free
            // normalize Al (plain division per reference)
            float vals[16];
            float lm = 0.0f;
#pragma unroll
            for (int n = 0; n < 16; n++) {
                int e = tid + 256 * n;
                float v = Al[(e >> 6) * ALS + (e & 63)];
                vals[n] = v;
                lm = fmaxf(lm, fabsf(v));
            }
            float amax = blk_max(lm, red, tid);
            if (tid == 0) accl += logf(amax);
            float sc = 1.0f / amax;
#pragma unroll
            for (int n = 0; n < 16; n++) {
                int e = tid + 256 * n;
                Al[(e >> 6) * ALS + (e & 63)] = vals[n] * sc;
            }
            bool outsite = ((i & 1) == 0) || (i == 255);
            if (outsite) {
                const float* Mg = mps_out + (size_t)16384 * ((i == 255) ? 128 : (i >> 1));
                lognorm_site<4>(Mg, Al, M, Tr, tid);
            } else {
                const float* Mg = mps_in + (size_t)8192 * i_in;
                i_in++;
                lognorm_site<2>(Mg, Al, M, Tr, tid);
            }
        }
        __syncthreads();
        if (tid == 0) {
            accl += logf(Al[0]);  // scals.append(Al[0,0]); log (no abs, no eps)
            ws[64] = accl;
        }
    } else {
        // ---------------- batched <psi|psi> chain ----------------
        const int b = blockIdx.x;
        float* Al  = smem;             // [64][66]  env matrix
        float* Ain = smem + 4224;      // [64][66]  normalized input-site matrix
        float* A0p = smem + 2 * 4224;  // [64][66]  A_{j=0}[l][r]
        float* A1p = smem + 3 * 4224;  // [64][66]  A_{j=1}[l][r]
        float* X0  = smem + 4 * 4224;  // [64][66]  x_0[dd][r], reused as T_0[l][u]
        float* X1  = smem + 5 * 4224;  // [64][66]  x_1 / T_1
        float* A0s = smem + 6 * 4224;  // [64][2]
        float* red = A0s + 128;        // [4]
        const int tx = tid & 15, ty = tid >> 4;
        const int r0 = 4 * ty, c0 = 4 * tx;
        float accl = 0.0f;

        // site 0: A0[r][j] = sum_i inp[0][b][i] * mps_out[0][0][r][i][j]; Al = A0 A0^T
        {
            float iv0 = inp[b * 2 + 0], iv1 = inp[b * 2 + 1];
            if (tid < 128) {
                int r = tid >> 1, j = tid & 1;
                A0s[tid] = iv0 * mps_out[r * 4 + j] + iv1 * mps_out[r * 4 + 2 + j];
            }
            __syncthreads();
            float vals[16];
            float lm = 0.0f;
#pragma unroll
            for (int n = 0; n < 16; n++) {
                int e = tid + 256 * n;
                int u = e >> 6, dd2 = e & 63;
                float v = A0s[2 * u] * A0s[2 * dd2] + A0s[2 * u + 1] * A0s[2 * dd2 + 1];
                vals[n] = v;
                lm = fmaxf(lm, fabsf(v));
            }
            float amax = blk_max(lm, red, tid);
            if (tid == 0) accl += logf(amax);
            float sc = (amax > 0.0f) ? 1.0f / amax : 0.0f;
#pragma unroll
            for (int n = 0; n < 16; n++) {
                int e = tid + 256 * n;
                Al[(e >> 6) * PADB + (e & 63)] = vals[n] * sc;
            }
        }

        for (int k = 1; k <= 127; k++) {
            // ---- input site i = 2k-1: Ain = normalize(sum_i inp*Min) ----
            {
                const float* Min = mps_in + (size_t)(k - 1) * 8192;
                int si = 2 * k - 1;
                float jv0 = inp[(si * 64 + b) * 2], jv1 = inp[(si * 64 + b) * 2 + 1];
                float vals[16];
                float lm = 0.0f;
#pragma unroll
                for (int n = 0; n < 16; n++) {
                    int e = tid + 256 * n;  // e = l*64 + r
                    float2 m2 = *reinterpret_cast<const float2*>(Min + 2 * e);
                    float v = jv0 * m2.x + jv1 * m2.y;
                    vals[n] = v;
                    lm = fmaxf(lm, fabsf(v));
                }
                float amax = blk_max(lm, red, tid);  // first sync orders prev-iter LDS traffic
                if (tid == 0) accl += 2.0f * logf(amax);  // out_S contribution
                float sc = (amax > 0.0f) ? 1.0f / amax : 0.0f;
#pragma unroll
                for (int n = 0; n < 16; n++) {
                    int e = tid + 256 * n;
                    Ain[(e >> 6) * PADB + (e & 63)] = vals[n] * sc;
                }
            }
            // ---- x_j[dd][r] = sum_i inp[2k]*mps_out[k][dd][r][i][j] ----
            {
                const float* Mo = mps_out + (size_t)k * 16384;
                int si = 2 * k;
                float ov0 = inp[(si * 64 + b) * 2], ov1 = inp[(si * 64 + b) * 2 + 1];
#pragma unroll
                for (int n = 0; n < 16; n++) {
                    int e = tid + 256 * n;  // e = dd*64 + r
                    int dd2 = e >> 6, r = e & 63;
                    float4 m = *reinterpret_cast<const float4*>(Mo + 4 * e);
                    X0[dd2 * PADB + r] = ov0 * m.x + ov1 * m.z;
                    X1[dd2 * PADB + r] = ov0 * m.y + ov1 * m.w;
                }
            }
            __syncthreads();  // Ain + x ready
            // ---- A_j[l][r] = sum_dd Ain[l][dd] * x_j[dd][r] ----
            {
                float a0[16], a1[16];
#pragma unroll
                for (int q = 0; q < 16; q++) { a0[q] = 0.f; a1[q] = 0.f; }
                for (int dd2 = 0; dd2 < 64; dd2++) {
                    float ai[4], x0v[4], x1v[4];
#pragma unroll
                    for (int c = 0; c < 4; c++) ai[c] = Ain[(r0 + c) * PADB + dd2];
#pragma unroll
                    for (int c = 0; c < 4; c++) {
                        x0v[c] = X0[dd2 * PADB + c0 + c];
                        x1v[c] = X1[dd2 * PADB + c0 + c];
                    }
#pragma unroll
                    for (int i2 = 0; i2 < 4; i2++)
#pragma unroll
                        for (int c = 0; c < 4; c++) {
                            a0[4 * i2 + c] += ai[i2] * x0v[c];
                            a1[4 * i2 + c] += ai[i2] * x1v[c];
                        }
                }
#pragma unroll
                for (int i2 = 0; i2 < 4; i2++)
#pragma unroll
                    for (int c = 0; c < 4; c++) {
                        A0p[(r0 + i2) * PADB + c0 + c] = a0[4 * i2 + c];
                        A1p[(r0 + i2) * PADB + c0 + c] = a1[4 * i2 + c];
                    }
            }
            __syncthreads();  // A ready; x reads done -> X planes reusable as T
            // ---- T_j[l][u] = sum_dd A_j[dd][l] * Al[dd][u] ----
            {
                float t0[16], t1[16];
#pragma unroll
                for (int q = 0; q < 16; q++) { t0[q] = 0.f; t1[q] = 0.f; }
                for (int dd2 = 0; dd2 < 64; dd2++) {
                    float aj0[4], aj1[4], alv[4];
#pragma unroll
                    for (int c = 0; c < 4; c++) {
                        aj0[c] = A0p[dd2 * PADB + r0 + c];
                        aj1[c] = A1p[dd2 * PADB + r0 + c];
                        alv[c] = Al[dd2 * PADB + c0 + c];
                    }
#pragma unroll
                    for (int i2 = 0; i2 < 4; i2++)
#pragma unroll
                        for (int c = 0; c < 4; c++) {
                            t0[4 * i2 + c] += aj0[i2] * alv[c];
                            t1[4 * i2 + c] += aj1[i2] * alv[c];
                        }
                }
#pragma unroll
                for (int i2 = 0; i2 < 4; i2++)
#pragma unroll
                    for (int c = 0; c < 4; c++) {
                        X0[(r0 + i2) * PADB + c0 + c] = t0[4 * i2 + c];
                        X1[(r0 + i2) * PADB + c0 + c] = t1[4 * i2 + c];
                    }
            }
            __syncthreads();  // T ready
            // ---- Al_new[l][r] = sum_{u,j} T_j[l][u] * A_j[u][r]; normalize ----
            {
                float acc[16];
#pragma unroll
                for (int q = 0; q < 16; q++) acc[q] = 0.f;
                for (int u = 0; u < 64; u++) {
                    float tt0[4], tt1[4], av0[4], av1[4];
#pragma unroll
                    for (int c = 0; c < 4; c++) {
                        tt0[c] = X0[(r0 + c) * PADB + u];
                        tt1[c] = X1[(r0 + c) * PADB + u];
                        av0[c] = A0p[u * PADB + c0 + c];
                        av1[c] = A1p[u * PADB + c0 + c];
                    }
#pragma unroll
                    for (int i2 = 0; i2 < 4; i2++)
#pragma unroll
                        for (int c = 0; c < 4; c++)
                            acc[4 * i2 + c] += tt0[i2] * av0[c] + tt1[i2] * av1[c];
                }
                float lm = 0.f;
#pragma unroll
                for (int q = 0; q < 16; q++) lm = fmaxf(lm, fabsf(acc[q]));
                float amax = blk_max(lm, red, tid);
                if (tid == 0) accl += logf(amax);
                float sc = (amax > 0.0f) ? 1.0f / amax : 0.0f;
#pragma unroll
                for (int i2 = 0; i2 < 4; i2++)
#pragma unroll
                    for (int c = 0; c < 4; c++)
                        Al[(r0 + i2) * PADB + c0 + c] = acc[4 * i2 + c] * sc;
            }
        }

        // ---- final site i=255: Afin[dd][j] from mps_out[128][:, :1];
        //      v = sum_{dd,u,j} Al[dd][u] Afin[dd][j] Afin[u][j] ----
        {
            const float* Mo = mps_out + (size_t)128 * 16384;
            float fv0 = inp[(255 * 64 + b) * 2], fv1 = inp[(255 * 64 + b) * 2 + 1];
            __syncthreads();
            if (tid < 128) {
                int dd2 = tid >> 1, jj = tid & 1;
                A0s[tid] = fv0 * Mo[dd2 * 256 + jj] + fv1 * Mo[dd2 * 256 + 2 + jj];
            }
            __syncthreads();
            float part = 0.0f;
#pragma unroll
            for (int n = 0; n < 16; n++) {
                int e = tid + 256 * n;
                int dd2 = e >> 6, u = e & 63;
                part += Al[dd2 * PADB + u] *
                        (A0s[2 * dd2] * A0s[2 * u] + A0s[2 * dd2 + 1] * A0s[2 * u + 1]);
            }
#pragma unroll
            for (int off = 32; off > 0; off >>= 1)
                part += __shfl_xor(part, off, 64);
            __syncthreads();
            if ((tid & 63) == 0) red[tid >> 6] = part;
            __syncthreads();
            if (tid == 0) {
                float v = red[0] + red[1] + red[2] + red[3];
                accl += logf(fabsf(v));  // |amax| term; log(|Al00/amax|)=log(1)=0
                ws[b] = accl;
            }
        }
    }
}

__global__ void proj_combine(const float* __restrict__ ws, float* __restrict__ out, int n) {
    int t = threadIdx.x;
    if (t < n) out[t] = ws[t] - ws[64];
}

extern "C" void kernel_launch(void* const* d_in, const int* in_sizes, int n_in,
                              void* d_out, int out_size, void* d_ws, size_t ws_size,
                              hipStream_t stream) {
    const float* inp = (const float*)d_in[0];
    const float* mi  = (const float*)d_in[1];
    const float* mo  = (const float*)d_in[2];
    float* ws = (float*)d_ws;
    proj_chain<<<dim3(65), dim3(256), 0, stream>>>(inp, mi, mo, ws);
    proj_combine<<<dim3(1), dim3(64), 0, stream>>>(ws, (float*)d_out, out_size);
}

// Round 2
// 1017.765 us; speedup vs baseline: 4.7651x; 4.7651x over previous
//
#include <hip/hip_runtime.h>
#include <math.h>

// Projector MPS chain, N=256, S=2, D=64, d=2, B=64, NOUT=129, NIN=127.
// MFMA (16x16x32 bf16) version. Blocks 0..63: per-batch <psi|psi> chain -> ws[b];
// block 64: _log_norm chain -> ws[64]. Kernel 2: out[b] = ws[b] - ws[64].

typedef __attribute__((ext_vector_type(8))) short short8;   // 8 bf16 (4 VGPRs)
typedef __attribute__((ext_vector_type(4))) float f32x4;

#define MFMA16(a, b, c) __builtin_amdgcn_mfma_f32_16x16x32_bf16(a, b, c, 0, 0, 0)

#define ST 72          // row stride (u16) for 64-wide bf16 planes; 144B rows (16B-aligned)
#define PL 4608        // 64*72 plane
// batch-path planes (8*PL = 36864 u16)
#define B_AIN 0
#define B_AL  PL
#define B_X0  (2 * PL)
#define B_X1  (3 * PL)
#define B_A0  (4 * PL)
#define B_A1  (5 * PL)
#define B_T0  (6 * PL)
#define B_T1  (7 * PL)
// lognorm planes
#define L_AL  0
#define L_MF  PL                  // MflatT: 256*72 = 18432
#define L_MT  (PL + 18432)        // Mtt: 4 planes * PL
#define L_T   (L_MT + 4 * PL)     // T: 64 * 264 = 16896
#define SU_SIZE (L_T + 64 * 264)  // 58368 u16 = 116736 B

__device__ __forceinline__ ushort f2b(float f) {  // fp32 -> bf16 RTNE
    union { float f; unsigned u; } x; x.f = f;
    return (ushort)((x.u + 0x7FFFu + ((x.u >> 16) & 1u)) >> 16);
}
__device__ __forceinline__ float b2f(ushort h) {
    union { unsigned u; float f; } x; x.u = ((unsigned)h) << 16; return x.f;
}
__device__ __forceinline__ short8 ldfrag(const ushort* p) {
    return *reinterpret_cast<const short8*>(p);  // ds_read_b128 (addresses 16B-aligned)
}

__device__ __forceinline__ float blk_max(float v, float* red, int tid) {
#pragma unroll
    for (int off = 32; off > 0; off >>= 1)
        v = fmaxf(v, __shfl_xor(v, off, 64));
    __syncthreads();
    if ((tid & 63) == 0) red[tid >> 6] = v;
    __syncthreads();
    return fmaxf(fmaxf(red[0], red[1]), fmaxf(red[2], red[3]));
}

// One _log_norm site: Al <- sum_{ij} M_ij^T Al M_ij  via 2 MFMA stages.
// MM1: C1[kij][u] = sum_d M[d][k,ij]*Al[d][u]  (A = MflatT rows kij, B = Al (symmetric))
// MM2: Al'[k][l] = sum_{ij,u} T[k][ij*64+u]*Mtt_ij[l-role]  accumulate over ij.
template <int QW>
__device__ __forceinline__ void ln_site(const float* __restrict__ Mg, ushort* su,
                                        float* red, int tid, float& accl) {
    constexpr int TSx = 64 * QW + 8;  // T row stride (u16); *2 bytes is 16B-multiple
    const int w = tid >> 6, g = (tid >> 4) & 3, l15 = tid & 15, a63 = tid & 63;
    const f32x4 fz = {0.f, 0.f, 0.f, 0.f};

    // ---- stage M (d-major lane assignment: conflict-free u16 LDS writes) ----
#pragma unroll
    for (int n = 0; n < 4 * QW; n++) {
        int m = (tid >> 6) + 4 * n;                         // 0..16*QW-1
        f32x4 v = *reinterpret_cast<const f32x4*>(Mg + 4 * (a63 * (16 * QW) + m));
        // MflatT[kij][d]: kij = 4m..4m+3 <-> v[0..3], d = a63
#pragma unroll
        for (int c = 0; c < 4; c++) su[L_MF + (4 * m + c) * ST + a63] = f2b(v[c]);
        if constexpr (QW == 4) {
            // Mtt_ij[l][u] = M[u=a63][l=m][ij=c]
#pragma unroll
            for (int c = 0; c < 4; c++) su[L_MT + c * PL + m * ST + a63] = f2b(v[c]);
        } else {
            su[L_MT + 0 * PL + (2 * m) * ST + a63]     = f2b(v[0]);
            su[L_MT + 1 * PL + (2 * m) * ST + a63]     = f2b(v[1]);
            su[L_MT + 0 * PL + (2 * m + 1) * ST + a63] = f2b(v[2]);
            su[L_MT + 1 * PL + (2 * m + 1) * ST + a63] = f2b(v[3]);
        }
    }
    __syncthreads();

    // ---- MM1: rows strip per wave = [16*QW*w, 16*QW*(w+1)) ----
    f32x4 acc1[QW][4];
#pragma unroll
    for (int tr = 0; tr < QW; tr++)
#pragma unroll
        for (int tc = 0; tc < 4; tc++) acc1[tr][tc] = fz;
#pragma unroll
    for (int ks = 0; ks < 2; ks++) {
        short8 bl[4];
#pragma unroll
        for (int tc = 0; tc < 4; tc++)
            bl[tc] = ldfrag(su + L_AL + (l15 + 16 * tc) * ST + 32 * ks + 8 * g);
#pragma unroll
        for (int tr = 0; tr < QW; tr++) {
            short8 af = ldfrag(su + L_MF + (16 * QW * w + 16 * tr + l15) * ST + 32 * ks + 8 * g);
#pragma unroll
            for (int tc = 0; tc < 4; tc++) acc1[tr][tc] = MFMA16(af, bl[tc], acc1[tr][tc]);
        }
    }
    // write T[k][ij*64+u]
#pragma unroll
    for (int tr = 0; tr < QW; tr++)
#pragma unroll
        for (int tc = 0; tc < 4; tc++)
#pragma unroll
            for (int r2 = 0; r2 < 4; r2++) {
                int m = 16 * QW * w + 16 * tr + 4 * g + r2;  // = kij
                su[L_T + (m / QW) * TSx + (m % QW) * 64 + l15 + 16 * tc] = f2b(acc1[tr][tc][r2]);
            }
    __syncthreads();

    // ---- MM2 ----
    f32x4 acc2[4];
#pragma unroll
    for (int tc = 0; tc < 4; tc++) acc2[tc] = fz;
#pragma unroll
    for (int ij = 0; ij < QW; ij++)
#pragma unroll
        for (int ks = 0; ks < 2; ks++) {
            short8 af = ldfrag(su + L_T + (16 * w + l15) * TSx + ij * 64 + 32 * ks + 8 * g);
#pragma unroll
            for (int tc = 0; tc < 4; tc++) {
                short8 bf_ = ldfrag(su + L_MT + ij * PL + (l15 + 16 * tc) * ST + 32 * ks + 8 * g);
                acc2[tc] = MFMA16(af, bf_, acc2[tc]);
            }
        }
    float lm = 0.f;
#pragma unroll
    for (int tc = 0; tc < 4; tc++)
#pragma unroll
        for (int r2 = 0; r2 < 4; r2++) lm = fmaxf(lm, fabsf(acc2[tc][r2]));
    float amax = blk_max(lm, red, tid);
    if (tid == 0) accl += logf(amax);
    float sc = 1.f / amax;
#pragma unroll
    for (int tc = 0; tc < 4; tc++)
#pragma unroll
        for (int r2 = 0; r2 < 4; r2++)
            su[L_AL + (16 * w + 4 * g + r2) * ST + l15 + 16 * tc] = f2b(acc2[tc][r2] * sc);
}

__global__ __launch_bounds__(256) void proj_chain(
    const float* __restrict__ inp,      // [256][64][2]
    const float* __restrict__ mps_in,   // [127][64][64][2]
    const float* __restrict__ mps_out,  // [129][64][64][2][2]
    float* __restrict__ ws)             // [65]
{
    __shared__ __align__(16) ushort su[SU_SIZE];
    __shared__ float fsc[132];
    float* A0s = fsc;        // [128]
    float* red = fsc + 128;  // [4]
    const int tid = threadIdx.x;
    const int w = tid >> 6, g = (tid >> 4) & 3, l15 = tid & 15;
    const f32x4 fz = {0.f, 0.f, 0.f, 0.f};
    float accl = 0.f;

    if (blockIdx.x == 64) {
        // ================= _log_norm chain =================
#pragma unroll
        for (int n = 0; n < 9; n++)
            reinterpret_cast<unsigned*>(su + L_AL)[tid + 256 * n] = 0u;  // 2304 u32
        if (tid == 0) su[L_AL] = (ushort)0x3F80;  // bf16 1.0 at Al[0][0]
        int i_in = 0;
        for (int i = 0; i < 256; i++) {
            __syncthreads();
            if ((i & 1) == 0 || i == 255) {
                const float* Mg = mps_out + (size_t)16384 * ((i == 255) ? 128 : (i >> 1));
                ln_site<4>(Mg, su, red, tid, accl);
            } else {
                ln_site<2>(mps_in + (size_t)8192 * (i_in++), su, red, tid, accl);
            }
        }
        __syncthreads();
        if (tid == 0) { accl += logf(b2f(su[L_AL])); ws[64] = accl; }
        return;
    }

    // ================= batched <psi|psi> chain =================
    const int b = blockIdx.x;

    // ---- site 0: A0[r][j]; Al = A0 A0^T (fp32, then bf16 row-major) ----
    {
        float iv0 = inp[b * 2 + 0], iv1 = inp[b * 2 + 1];
        if (tid < 128) {
            int r = tid >> 1, j = tid & 1;
            A0s[tid] = iv0 * mps_out[r * 4 + j] + iv1 * mps_out[r * 4 + 2 + j];
        }
        __syncthreads();
        float vals[16];
        float lm = 0.f;
#pragma unroll
        for (int n = 0; n < 16; n++) {
            int e = tid + 256 * n;
            int u = e >> 6, d2 = e & 63;
            float v = A0s[2 * u] * A0s[2 * d2] + A0s[2 * u + 1] * A0s[2 * d2 + 1];
            vals[n] = v;
            lm = fmaxf(lm, fabsf(v));
        }
        float amax = blk_max(lm, red, tid);
        if (tid == 0) accl += logf(amax);
        float sc = (amax > 0.f) ? 1.f / amax : 0.f;
#pragma unroll
        for (int n = 0; n < 16; n++) {
            int e = tid + 256 * n;
            su[B_AL + (e >> 6) * ST + (e & 63)] = f2b(vals[n] * sc);
        }
    }

    for (int k = 1; k <= 127; k++) {
        __syncthreads();
        const float* Min = mps_in + (size_t)(k - 1) * 8192;
        const float* Mo = mps_out + (size_t)k * 16384;
        float jv0 = inp[((2 * k - 1) * 64 + b) * 2], jv1 = inp[((2 * k - 1) * 64 + b) * 2 + 1];
        float ov0 = inp[((2 * k) * 64 + b) * 2],     ov1 = inp[((2 * k) * 64 + b) * 2 + 1];
        // ---- stage Ain (row-major [l][dd], unnormalized: log bookkeeping folds) ----
#pragma unroll
        for (int n = 0; n < 8; n++) {
            int f = tid + 256 * n;
            f32x4 v = *reinterpret_cast<const f32x4*>(Min + 4 * f);
            int l = f >> 5, dd = (2 * f) & 63;
            unsigned pk = (unsigned)f2b(jv0 * v[0] + jv1 * v[1]) |
                          ((unsigned)f2b(jv0 * v[2] + jv1 * v[3]) << 16);
            *reinterpret_cast<unsigned*>(su + B_AIN + l * ST + dd) = pk;
        }
        // ---- stage X_j transposed [r][dd] (d-major lanes: conflict-free writes) ----
        {
            int a63 = tid & 63, hi = tid >> 6;
#pragma unroll
            for (int n = 0; n < 16; n++) {
                int r = hi + 4 * n;
                f32x4 v = *reinterpret_cast<const f32x4*>(Mo + 4 * (a63 * 64 + r));
                su[B_X0 + r * ST + a63] = f2b(ov0 * v[0] + ov1 * v[2]);
                su[B_X1 + r * ST + a63] = f2b(ov0 * v[1] + ov1 * v[3]);
            }
        }
        __syncthreads();
        // ---- MM1: A_j = Ain * X_j ----
        f32x4 accA[2][4];
#pragma unroll
        for (int j = 0; j < 2; j++)
#pragma unroll
            for (int tc = 0; tc < 4; tc++) accA[j][tc] = fz;
#pragma unroll
        for (int ks = 0; ks < 2; ks++) {
            short8 af = ldfrag(su + B_AIN + (16 * w + l15) * ST + 32 * ks + 8 * g);
#pragma unroll
            for (int j = 0; j < 2; j++)
#pragma unroll
                for (int tc = 0; tc < 4; tc++) {
                    short8 bf_ = ldfrag(su + (j ? B_X1 : B_X0) + (l15 + 16 * tc) * ST + 32 * ks + 8 * g);
                    accA[j][tc] = MFMA16(af, bf_, accA[j][tc]);
                }
        }
        // write A_j transposed: AjT[col][row]
#pragma unroll
        for (int j = 0; j < 2; j++)
#pragma unroll
            for (int tc = 0; tc < 4; tc++)
#pragma unroll
                for (int r2 = 0; r2 < 4; r2++)
                    su[(j ? B_A1 : B_A0) + (l15 + 16 * tc) * ST + 16 * w + 4 * g + r2] =
                        f2b(accA[j][tc][r2]);
        __syncthreads();
        // ---- MM2: T_j = A_j^T * Al  (Al symmetric -> row-major serves as B) ----
        f32x4 accT[2][4];
#pragma unroll
        for (int j = 0; j < 2; j++)
#pragma unroll
            for (int tc = 0; tc < 4; tc++) accT[j][tc] = fz;
#pragma unroll
        for (int ks = 0; ks < 2; ks++) {
            short8 a0f = ldfrag(su + B_A0 + (16 * w + l15) * ST + 32 * ks + 8 * g);
            short8 a1f = ldfrag(su + B_A1 + (16 * w + l15) * ST + 32 * ks + 8 * g);
#pragma unroll
            for (int tc = 0; tc < 4; tc++) {
                short8 bl = ldfrag(su + B_AL + (l15 + 16 * tc) * ST + 32 * ks + 8 * g);
                accT[0][tc] = MFMA16(a0f, bl, accT[0][tc]);
                accT[1][tc] = MFMA16(a1f, bl, accT[1][tc]);
            }
        }
        // write T_j row-major [row][u] -- wave-local strip, no barrier needed before MM3
#pragma unroll
        for (int j = 0; j < 2; j++)
#pragma unroll
            for (int tc = 0; tc < 4; tc++)
#pragma unroll
                for (int r2 = 0; r2 < 4; r2++)
                    su[(j ? B_T1 : B_T0) + (16 * w + 4 * g + r2) * ST + l15 + 16 * tc] =
                        f2b(accT[j][tc][r2]);
        // ---- MM3: AlNew = sum_j T_j * A_j ----
        f32x4 accN[4];
#pragma unroll
        for (int tc = 0; tc < 4; tc++) accN[tc] = fz;
#pragma unroll
        for (int j = 0; j < 2; j++)
#pragma unroll
            for (int ks = 0; ks < 2; ks++) {
                short8 tf = ldfrag(su + (j ? B_T1 : B_T0) + (16 * w + l15) * ST + 32 * ks + 8 * g);
#pragma unroll
                for (int tc = 0; tc < 4; tc++) {
                    short8 bf_ = ldfrag(su + (j ? B_A1 : B_A0) + (l15 + 16 * tc) * ST + 32 * ks + 8 * g);
                    accN[tc] = MFMA16(tf, bf_, accN[tc]);
                }
            }
        float lm = 0.f;
#pragma unroll
        for (int tc = 0; tc < 4; tc++)
#pragma unroll
            for (int r2 = 0; r2 < 4; r2++) lm = fmaxf(lm, fabsf(accN[tc][r2]));
        float amax = blk_max(lm, red, tid);
        if (tid == 0) accl += logf(amax);
        float sc = (amax > 0.f) ? 1.f / amax : 0.f;
#pragma unroll
        for (int tc = 0; tc < 4; tc++)
#pragma unroll
            for (int r2 = 0; r2 < 4; r2++)
                su[B_AL + (16 * w + 4 * g + r2) * ST + l15 + 16 * tc] = f2b(accN[tc][r2] * sc);
    }

    // ---- final site i=255 ----
    {
        const float* Mo = mps_out + (size_t)128 * 16384;
        float fv0 = inp[(255 * 64 + b) * 2], fv1 = inp[(255 * 64 + b) * 2 + 1];
        __syncthreads();
        if (tid < 128) {
            int d2 = tid >> 1, jj = tid & 1;
            A0s[tid] = fv0 * Mo[d2 * 256 + jj] + fv1 * Mo[d2 * 256 + 2 + jj];
        }
        __syncthreads();
        float part = 0.f;
#pragma unroll
        for (int n = 0; n < 16; n++) {
            int e = tid + 256 * n;
            int d2 = e >> 6, u = e & 63;
            part += b2f(su[B_AL + d2 * ST + u]) *
                    (A0s[2 * d2] * A0s[2 * u] + A0s[2 * d2 + 1] * A0s[2 * u + 1]);
        }
#pragma unroll
        for (int off = 32; off > 0; off >>= 1)
            part += __shfl_xor(part, off, 64);
        __syncthreads();
        if ((tid & 63) == 0) red[tid >> 6] = part;
        __syncthreads();
        if (tid == 0) {
            float v = red[0] + red[1] + red[2] + red[3];
            accl += logf(fabsf(v));
            ws[b] = accl;
        }
    }
}

__global__ void proj_combine(const float* __restrict__ ws, float* __restrict__ out, int n) {
    int t = threadIdx.x;
    if (t < n) out[t] = ws[t] - ws[64];
}

extern "C" void kernel_launch(void* const* d_in, const int* in_sizes, int n_in,
                              void* d_out, int out_size, void* d_ws, size_t ws_size,
                              hipStream_t stream) {
    const float* inp = (const float*)d_in[0];
    const float* mi  = (const float*)d_in[1];
    const float* mo  = (const float*)d_in[2];
    float* ws = (float*)d_ws;
    proj_chain<<<dim3(65), dim3(256), 0, stream>>>(inp, mi, mo, ws);
    proj_combine<<<dim3(1), dim3(64), 0, stream>>>(ws, (float*)d_out, out_size);
}

// Round 3
// 665.107 us; speedup vs baseline: 7.2916x; 1.5302x over previous
//
#include <hip/hip_runtime.h>
#include <math.h>

// Projector MPS chain, N=256, S=2, D=64, d=2, B=64, NOUT=129, NIN=127.
// MFMA 16x16x32 bf16, 2-barrier/site pipeline, register prefetch, raw barriers.
// Blocks 0..63: per-batch <psi|psi> chain -> ws[b]; block 64: _log_norm -> ws[64].

typedef __attribute__((ext_vector_type(8))) short short8;   // 8 bf16
typedef __attribute__((ext_vector_type(4))) float f32x4;

#define MFMA16(a, b, c) __builtin_amdgcn_mfma_f32_16x16x32_bf16(a, b, c, 0, 0, 0)

#define ST 72          // row stride (u16): 144 B rows, 16B-aligned
#define PL 4608        // 64*ST plane
// batch planes (12 * PL = 55296 u16)
#define B_AIN(p) ((0 + (p)) * PL)
#define B_X0(p)  ((2 + (p)) * PL)
#define B_X1(p)  ((4 + (p)) * PL)
#define B_A0T    (6 * PL)
#define B_A1T    (7 * PL)
#define B_T0     (8 * PL)
#define B_T1     (9 * PL)
#define B_ALP(p) ((10 + (p)) * PL)
// lognorm planes
#define L_AL     0
#define L_MF(p)  (PL + (p) * 18432)     // MflatT [m][d], 2 buffers (256*ST max)
#define L_T      (PL + 2 * 18432)       // T [64][TSx], TSx<=264
#define SU_U16   (PL + 2 * 18432 + 64 * 264)   // 58368 u16 = 116736 B

// raw barrier: order LDS, leave global prefetch loads in flight (no vmcnt drain)
#define BARRIER() do { asm volatile("s_waitcnt lgkmcnt(0)" ::: "memory"); \
                       __builtin_amdgcn_s_barrier(); } while (0)

__device__ __forceinline__ unsigned pk2(float lo, float hi) {  // 2x f32 -> packed bf16
    unsigned r;
    asm("v_cvt_pk_bf16_f32 %0, %1, %2" : "=v"(r) : "v"(lo), "v"(hi));
    return r;
}
__device__ __forceinline__ ushort f2b(float f) {
    union { float f; unsigned u; } x; x.f = f;
    return (ushort)((x.u + 0x7FFFu + ((x.u >> 16) & 1u)) >> 16);
}
__device__ __forceinline__ float b2f(ushort h) {
    union { unsigned u; float f; } x; x.u = ((unsigned)h) << 16; return x.f;
}
__device__ __forceinline__ short8 ldfrag(const ushort* p) {
    return *reinterpret_cast<const short8*>(p);  // ds_read_b128
}
__device__ __forceinline__ void st64(ushort* p, unsigned lo, unsigned hi) {
    unsigned long long v = ((unsigned long long)hi << 32) | (unsigned long long)lo;
    *reinterpret_cast<unsigned long long*>(p) = v;  // ds_write_b64 (8B-aligned)
}

__device__ __forceinline__ float blk_max(float v, float* red, int tid) {
#pragma unroll
    for (int off = 32; off > 0; off >>= 1)
        v = fmaxf(v, __shfl_xor(v, off, 64));
    BARRIER();
    if ((tid & 63) == 0) red[tid >> 6] = v;
    BARRIER();
    return fmaxf(fmaxf(red[0], red[1]), fmaxf(red[2], red[3]));
}

// ---------------- lognorm helpers ----------------
template <int NQ>
__device__ __forceinline__ void ln_stageMF(ushort* su, int mfb, const f32x4 (&pf)[16], int tid) {
    const int a63 = tid & 63, hi = tid >> 6;
#pragma unroll
    for (int n = 0; n < 4 * NQ; n++) {
        int m = hi + 4 * n;
        unsigned p01 = pk2(pf[n][0], pf[n][1]);
        unsigned p23 = pk2(pf[n][2], pf[n][3]);
        su[mfb + (4 * m + 0) * ST + a63] = (ushort)(p01 & 0xFFFFu);
        su[mfb + (4 * m + 1) * ST + a63] = (ushort)(p01 >> 16);
        su[mfb + (4 * m + 2) * ST + a63] = (ushort)(p23 & 0xFFFFu);
        su[mfb + (4 * m + 3) * ST + a63] = (ushort)(p23 >> 16);
    }
}
__device__ __forceinline__ void ln_loadPF(f32x4 (&pf)[16], const float* g_, int qw, int tid) {
    const int a63 = tid & 63, hi = tid >> 6;
#pragma unroll
    for (int n = 0; n < 16; n++)
        if (n < 4 * qw)
            pf[n] = *reinterpret_cast<const f32x4*>(g_ + 4 * ((size_t)a63 * (16 * qw) + hi + 4 * n));
}

// phase A: MM1 C1[m][u] = sum_d MF[m][d]*Al[d][u]; write T[k][ij*64+u]; stage next MF
template <int QW>
__device__ __forceinline__ void ln_phaseA(ushort* su, int mfp, int tid,
                                          f32x4 (&pf)[16], const float* nMg, int nQW) {
    constexpr int TSx = 64 * QW + 8;
    const int w = tid >> 6, g = (tid >> 4) & 3, l15 = tid & 15;
    const int mfb = L_MF(mfp);
    const f32x4 fz = {0.f, 0.f, 0.f, 0.f};
    f32x4 acc1[QW][4];
#pragma unroll
    for (int tr = 0; tr < QW; tr++)
#pragma unroll
        for (int tc = 0; tc < 4; tc++) acc1[tr][tc] = fz;
#pragma unroll
    for (int ks = 0; ks < 2; ks++) {
        short8 bl[4];
#pragma unroll
        for (int tc = 0; tc < 4; tc++)
            bl[tc] = ldfrag(su + L_AL + (l15 + 16 * tc) * ST + 32 * ks + 8 * g);
#pragma unroll
        for (int tr = 0; tr < QW; tr++) {
            short8 af = ldfrag(su + mfb + (16 * QW * w + 16 * tr + l15) * ST + 32 * ks + 8 * g);
#pragma unroll
            for (int tc = 0; tc < 4; tc++) acc1[tr][tc] = MFMA16(af, bl[tc], acc1[tr][tc]);
        }
    }
#pragma unroll
    for (int tr = 0; tr < QW; tr++)
#pragma unroll
        for (int tc = 0; tc < 4; tc++) {
            unsigned pa = pk2(acc1[tr][tc][0], acc1[tr][tc][1]);
            unsigned pb = pk2(acc1[tr][tc][2], acc1[tr][tc][3]);
            int m0 = 16 * QW * w + 16 * tr + 4 * g;
            int u = l15 + 16 * tc;
            su[L_T + ((m0 + 0) / QW) * TSx + ((m0 + 0) % QW) * 64 + u] = (ushort)(pa & 0xFFFFu);
            su[L_T + ((m0 + 1) / QW) * TSx + ((m0 + 1) % QW) * 64 + u] = (ushort)(pa >> 16);
            su[L_T + ((m0 + 2) / QW) * TSx + ((m0 + 2) % QW) * 64 + u] = (ushort)(pb & 0xFFFFu);
            su[L_T + ((m0 + 3) / QW) * TSx + ((m0 + 3) % QW) * 64 + u] = (ushort)(pb >> 16);
        }
    if (nMg) {
        if (nQW == 4) ln_stageMF<4>(su, L_MF(mfp ^ 1), pf, tid);
        else          ln_stageMF<2>(su, L_MF(mfp ^ 1), pf, tid);
    }
}

// phase B: MM2 Al'[k][l] = sum_{m2} T[k][m2] * MF[l*QW+ij][u]; (2x2 wave grid)
template <int QW>
__device__ __forceinline__ void ln_phaseB(ushort* su, int mfp, int tid,
                                          float* red, float& accl, bool donorm) {
    constexpr int TSx = 64 * QW + 8;
    const int w = tid >> 6, g = (tid >> 4) & 3, l15 = tid & 15;
    const int wr = w >> 1, wc = w & 1;
    const int mfb = L_MF(mfp);
    const f32x4 fz = {0.f, 0.f, 0.f, 0.f};
    f32x4 acc2[2][2];
#pragma unroll
    for (int rt = 0; rt < 2; rt++)
#pragma unroll
        for (int tc = 0; tc < 2; tc++) acc2[rt][tc] = fz;
#pragma unroll
    for (int kk = 0; kk < 2 * QW; kk++) {
        short8 af[2];
#pragma unroll
        for (int rt = 0; rt < 2; rt++)
            af[rt] = ldfrag(su + L_T + (32 * wr + 16 * rt + l15) * TSx + 32 * kk + 8 * g);
#pragma unroll
        for (int tc = 0; tc < 2; tc++) {
            short8 bf_ = ldfrag(su + mfb + ((32 * wc + 16 * tc + l15) * QW + (kk >> 1)) * ST +
                                (kk & 1) * 32 + 8 * g);
#pragma unroll
            for (int rt = 0; rt < 2; rt++) acc2[rt][tc] = MFMA16(af[rt], bf_, acc2[rt][tc]);
        }
    }
    float sc = 1.f;
    if (donorm) {
        float lm = 0.f;
#pragma unroll
        for (int rt = 0; rt < 2; rt++)
#pragma unroll
            for (int tc = 0; tc < 2; tc++)
#pragma unroll
                for (int r2 = 0; r2 < 4; r2++) lm = fmaxf(lm, fabsf(acc2[rt][tc][r2]));
        float amax = blk_max(lm, red, tid);
        if (tid == 0) accl += logf(amax);
        sc = 1.f / amax;
    }
    // Al' write: column-major pack == row-major by symmetry
#pragma unroll
    for (int rt = 0; rt < 2; rt++)
#pragma unroll
        for (int tc = 0; tc < 2; tc++) {
            unsigned lo_ = pk2(acc2[rt][tc][0] * sc, acc2[rt][tc][1] * sc);
            unsigned hi_ = pk2(acc2[rt][tc][2] * sc, acc2[rt][tc][3] * sc);
            st64(&su[L_AL + (32 * wc + 16 * tc + l15) * ST + 32 * wr + 16 * rt + 4 * g], lo_, hi_);
        }
}

__global__ __launch_bounds__(256, 1) void proj_chain(
    const float* __restrict__ inp,      // [256][64][2]
    const float* __restrict__ mps_in,   // [127][64][64][2]
    const float* __restrict__ mps_out,  // [129][64][64][2][2]
    float* __restrict__ ws)             // [65]
{
    __shared__ __align__(16) ushort su[SU_U16];
    __shared__ float fsc[132];
    float* A0s = fsc;
    float* red = fsc + 128;
    const int tid = threadIdx.x;
    const int w = tid >> 6, g = (tid >> 4) & 3, l15 = tid & 15;
    const int a63 = tid & 63, hi = tid >> 6;
    const f32x4 fz = {0.f, 0.f, 0.f, 0.f};
    float accl = 0.f;

    if (blockIdx.x == 64) {
        // ================= _log_norm chain =================
#pragma unroll
        for (int n = 0; n < 9; n++)
            reinterpret_cast<unsigned*>(su + L_AL)[tid + 256 * n] = 0u;
        if (tid == 0) su[L_AL] = (ushort)0x3F80;  // Al[0][0] = 1.0 bf16
        f32x4 pf[16];
        ln_loadPF(pf, mps_out, 4, tid);           // site 0
        ln_stageMF<4>(su, L_MF(0), pf, tid);
        ln_loadPF(pf, mps_in, 2, tid);            // site 1
        BARRIER();
        for (int i = 0; i < 256; i++) {
            int p = i & 1;
            bool cOut = ((i & 1) == 0) || (i == 255);
            int j = i + 1;
            const float* nMg = nullptr; int nQW = 4;
            if (j < 256) {
                bool nOut = ((j & 1) == 0) || (j == 255);
                if (nOut) { nQW = 4; nMg = mps_out + (size_t)16384 * ((j == 255) ? 128 : (j >> 1)); }
                else      { nQW = 2; nMg = mps_in + (size_t)8192 * (j >> 1); }
            }
            if (cOut) ln_phaseA<4>(su, p, tid, pf, nMg, nQW);
            else      ln_phaseA<2>(su, p, tid, pf, nMg, nQW);
            int j2 = i + 2;
            if (j2 < 256) {  // issue prefetch for site i+2 (in flight across barriers)
                bool n2Out = ((j2 & 1) == 0) || (j2 == 255);
                const float* n2Mg = n2Out ? mps_out + (size_t)16384 * ((j2 == 255) ? 128 : (j2 >> 1))
                                          : mps_in + (size_t)8192 * (j2 >> 1);
                ln_loadPF(pf, n2Mg, n2Out ? 4 : 2, tid);
            }
            BARRIER();
            bool donorm = ((i & 3) == 3) || (i == 255);
            if (cOut) ln_phaseB<4>(su, p, tid, red, accl, donorm);
            else      ln_phaseB<2>(su, p, tid, red, accl, donorm);
            BARRIER();
        }
        if (tid == 0) { accl += logf(b2f(su[L_AL])); ws[64] = accl; }
        return;
    }

    // ================= batched <psi|psi> chain =================
    const int b = blockIdx.x;
    int ap = 0, bs = 0;
    f32x4 pfA[8], pfX[16];

    auto loadPF = [&](int k) {  // site pair k: Min[k-1], Mo[k]
        const float* Min = mps_in + (size_t)(k - 1) * 8192;
        const float* Mo  = mps_out + (size_t)k * 16384;
#pragma unroll
        for (int n = 0; n < 8; n++)
            pfA[n] = *reinterpret_cast<const f32x4*>(Min + 4 * (tid + 256 * n));
#pragma unroll
        for (int n = 0; n < 16; n++)
            pfX[n] = *reinterpret_cast<const f32x4*>(Mo + 4 * ((size_t)a63 * 64 + hi + 4 * n));
    };
    auto stageAX = [&](int k, int buf) {
        float jv0 = inp[((2 * k - 1) * 64 + b) * 2], jv1 = inp[((2 * k - 1) * 64 + b) * 2 + 1];
        float ov0 = inp[((2 * k) * 64 + b) * 2],     ov1 = inp[((2 * k) * 64 + b) * 2 + 1];
#pragma unroll
        for (int n = 0; n < 8; n++) {
            int f = tid + 256 * n, l = f >> 5, dd = (2 * f) & 63;
            unsigned pkv = pk2(jv0 * pfA[n][0] + jv1 * pfA[n][1],
                               jv0 * pfA[n][2] + jv1 * pfA[n][3]);
            *reinterpret_cast<unsigned*>(&su[B_AIN(buf) + l * ST + dd]) = pkv;
        }
#pragma unroll
        for (int n = 0; n < 16; n++) {
            int r = hi + 4 * n;
            unsigned px = pk2(ov0 * pfX[n][0] + ov1 * pfX[n][2],
                              ov0 * pfX[n][1] + ov1 * pfX[n][3]);
            su[B_X0(buf) + r * ST + a63] = (ushort)(px & 0xFFFFu);
            su[B_X1(buf) + r * ST + a63] = (ushort)(px >> 16);
        }
    };

    loadPF(1);
    // ---- site 0 ----
    {
        float iv0 = inp[b * 2 + 0], iv1 = inp[b * 2 + 1];
        if (tid < 128) {
            int r = tid >> 1, jj = tid & 1;
            A0s[tid] = iv0 * mps_out[r * 4 + jj] + iv1 * mps_out[r * 4 + 2 + jj];
        }
        BARRIER();
        float vals[16];
        float lm = 0.f;
#pragma unroll
        for (int n = 0; n < 16; n++) {
            int e = tid + 256 * n;
            int u = e >> 6, d2 = e & 63;
            float v = A0s[2 * u] * A0s[2 * d2] + A0s[2 * u + 1] * A0s[2 * d2 + 1];
            vals[n] = v;
            lm = fmaxf(lm, fabsf(v));
        }
        float amax = blk_max(lm, red, tid);
        if (tid == 0) accl += logf(amax);
        float sc0 = (amax > 0.f) ? 1.f / amax : 0.f;
#pragma unroll
        for (int n = 0; n < 16; n++) {
            int e = tid + 256 * n;
            su[B_ALP(0) + (e >> 6) * ST + (e & 63)] = f2b(vals[n] * sc0);
        }
    }
    stageAX(1, 0);
    loadPF(2);
    BARRIER();

    for (int k = 1; k <= 127; k++) {
        // ---- phase A: MM1 A_j = Ain * X_j -> AjT (packed); stage next; prefetch ----
        {
            f32x4 accA[2][4];
#pragma unroll
            for (int j = 0; j < 2; j++)
#pragma unroll
                for (int tc = 0; tc < 4; tc++) accA[j][tc] = fz;
#pragma unroll
            for (int ks = 0; ks < 2; ks++) {
                short8 af_ = ldfrag(su + B_AIN(bs) + (16 * w + l15) * ST + 32 * ks + 8 * g);
#pragma unroll
                for (int j = 0; j < 2; j++)
#pragma unroll
                    for (int tc = 0; tc < 4; tc++) {
                        short8 bf_ = ldfrag(su + (j ? B_X1(bs) : B_X0(bs)) +
                                            (l15 + 16 * tc) * ST + 32 * ks + 8 * g);
                        accA[j][tc] = MFMA16(af_, bf_, accA[j][tc]);
                    }
            }
#pragma unroll
            for (int j = 0; j < 2; j++)
#pragma unroll
                for (int tc = 0; tc < 4; tc++) {
                    unsigned lo_ = pk2(accA[j][tc][0], accA[j][tc][1]);
                    unsigned hi_ = pk2(accA[j][tc][2], accA[j][tc][3]);
                    st64(&su[(j ? B_A1T : B_A0T) + (l15 + 16 * tc) * ST + 16 * w + 4 * g], lo_, hi_);
                }
            if (k < 127) { stageAX(k + 1, bs ^ 1); if (k <= 125) loadPF(k + 2); }
        }
        BARRIER();
        // ---- phase B: MM2 T_j = A_j^T * Al; MM3 Al' = sum_j T_j A_j ----
        {
            f32x4 accT[2][4];
#pragma unroll
            for (int j = 0; j < 2; j++)
#pragma unroll
                for (int tc = 0; tc < 4; tc++) accT[j][tc] = fz;
#pragma unroll
            for (int ks = 0; ks < 2; ks++) {
                short8 a0f = ldfrag(su + B_A0T + (16 * w + l15) * ST + 32 * ks + 8 * g);
                short8 a1f = ldfrag(su + B_A1T + (16 * w + l15) * ST + 32 * ks + 8 * g);
#pragma unroll
                for (int tc = 0; tc < 4; tc++) {
                    short8 bl = ldfrag(su + B_ALP(ap) + (l15 + 16 * tc) * ST + 32 * ks + 8 * g);
                    accT[0][tc] = MFMA16(a0f, bl, accT[0][tc]);
                    accT[1][tc] = MFMA16(a1f, bl, accT[1][tc]);
                }
            }
            // T writes: row-major, wave-local (read below by same wave)
#pragma unroll
            for (int j = 0; j < 2; j++)
#pragma unroll
                for (int tc = 0; tc < 4; tc++) {
                    unsigned pa = pk2(accT[j][tc][0], accT[j][tc][1]);
                    unsigned pb = pk2(accT[j][tc][2], accT[j][tc][3]);
                    int base = (j ? B_T1 : B_T0) + (16 * w + 4 * g) * ST + l15 + 16 * tc;
                    su[base]          = (ushort)(pa & 0xFFFFu);
                    su[base + ST]     = (ushort)(pa >> 16);
                    su[base + 2 * ST] = (ushort)(pb & 0xFFFFu);
                    su[base + 3 * ST] = (ushort)(pb >> 16);
                }
            f32x4 accN[4];
#pragma unroll
            for (int tc = 0; tc < 4; tc++) accN[tc] = fz;
#pragma unroll
            for (int j = 0; j < 2; j++)
#pragma unroll
                for (int ks = 0; ks < 2; ks++) {
                    short8 tf = ldfrag(su + (j ? B_T1 : B_T0) + (16 * w + l15) * ST + 32 * ks + 8 * g);
#pragma unroll
                    for (int tc = 0; tc < 4; tc++) {
                        short8 bf_ = ldfrag(su + (j ? B_A1T : B_A0T) +
                                            (l15 + 16 * tc) * ST + 32 * ks + 8 * g);
                        accN[tc] = MFMA16(tf, bf_, accN[tc]);
                    }
                }
            float sc = 1.f;
            bool donorm = ((k & 3) == 0);
            if (donorm) {
                float lm = 0.f;
#pragma unroll
                for (int tc = 0; tc < 4; tc++)
#pragma unroll
                    for (int r2 = 0; r2 < 4; r2++) lm = fmaxf(lm, fabsf(accN[tc][r2]));
                float amax = blk_max(lm, red, tid);
                if (tid == 0) accl += logf(amax);
                sc = (amax > 0.f) ? 1.f / amax : 0.f;
            }
            // Al' write: column-major pack == row-major by symmetry
#pragma unroll
            for (int tc = 0; tc < 4; tc++) {
                unsigned lo_ = pk2(accN[tc][0] * sc, accN[tc][1] * sc);
                unsigned hi_ = pk2(accN[tc][2] * sc, accN[tc][3] * sc);
                st64(&su[B_ALP(ap ^ 1) + (l15 + 16 * tc) * ST + 16 * w + 4 * g], lo_, hi_);
            }
            ap ^= 1; bs ^= 1;
        }
        BARRIER();
    }

    // ---- final site i=255 ----
    {
        const float* Mo = mps_out + (size_t)128 * 16384;
        float fv0 = inp[(255 * 64 + b) * 2], fv1 = inp[(255 * 64 + b) * 2 + 1];
        if (tid < 128) {
            int d2 = tid >> 1, jj = tid & 1;
            A0s[tid] = fv0 * Mo[d2 * 256 + jj] + fv1 * Mo[d2 * 256 + 2 + jj];
        }
        BARRIER();
        float part = 0.f;
#pragma unroll
        for (int n = 0; n < 16; n++) {
            int e = tid + 256 * n;
            int d2 = e >> 6, u = e & 63;
            part += b2f(su[B_ALP(ap) + d2 * ST + u]) *
                    (A0s[2 * d2] * A0s[2 * u] + A0s[2 * d2 + 1] * A0s[2 * u + 1]);
        }
#pragma unroll
        for (int off = 32; off > 0; off >>= 1)
            part += __shfl_xor(part, off, 64);
        BARRIER();
        if ((tid & 63) == 0) red[tid >> 6] = part;
        BARRIER();
        if (tid == 0) {
            float v = red[0] + red[1] + red[2] + red[3];
            accl += logf(fabsf(v));
            ws[b] = accl;
        }
    }
}

__global__ void proj_combine(const float* __restrict__ ws, float* __restrict__ out, int n) {
    int t = threadIdx.x;
    if (t < n) out[t] = ws[t] - ws[64];
}

extern "C" void kernel_launch(void* const* d_in, const int* in_sizes, int n_in,
                              void* d_out, int out_size, void* d_ws, size_t ws_size,
                              hipStream_t stream) {
    const float* inp = (const float*)d_in[0];
    const float* mi  = (const float*)d_in[1];
    const float* mo  = (const float*)d_in[2];
    float* ws = (float*)d_ws;
    proj_chain<<<dim3(65), dim3(256), 0, stream>>>(inp, mi, mo, ws);
    proj_combine<<<dim3(1), dim3(64), 0, stream>>>(ws, (float*)d_out, out_size);
}

// Round 5
// 622.931 us; speedup vs baseline: 7.7853x; 1.0677x over previous
//
#include <hip/hip_runtime.h>
#include <math.h>

// Projector MPS chain, N=256, S=2, D=64, d=2, B=64, NOUT=129, NIN=127.
// Preconv kernel: mps weights -> bf16 in chain-friendly layouts (in d_ws).
// proj_chain<BFS>: blocks 0..31 batch pairs (2 chains each) -> ws[b]; block 32 lognorm -> ws[64].
// 1 barrier/site (lognorm), 2 (batch); all MFMA C-writes are ds_write_b64; deferred scaling.

typedef __attribute__((ext_vector_type(8))) short short8;   // 8 bf16
typedef __attribute__((ext_vector_type(4))) float f32x4;

#define MFMA16(a, b, c) __builtin_amdgcn_mfma_f32_16x16x32_bf16(a, b, c, 0, 0, 0)

#define ST 72          // row stride (u16), 144 B rows
#define PL 4608        // 64*ST plane
#define BS 72          // lognorm T: ij-block stride
// lognorm LDS map (u16)
#define L_AL(q) ((q) * PL)                 // 2 planes
#define L_MF(p) (2 * PL + (p) * 18432)     // 2 x [256][72]
#define L_T     (2 * PL + 2 * 18432)       // [64][296] max = 18944
// batch LDS map: per bb 8 planes: 0 AIN,1 X0,2 X1,3 A0T,4 A1T,5 T0,6 T1,7 AL
#define BPL(b, i) (((b) * 8 + (i)) * PL)
#define SU_U16 (16 * PL)                   // 73728 u16 = 147456 B (>= lognorm 65024)

// ws u16 offsets (after 512-byte header holding ws[65] f32 results)
#define MINB 0ull
#define MOTB 1040384ull
#define MFIB 3153920ull
#define MFOB 4194304ull
#define WS_U16_TOT 6307840ull

#define BARRIER() do { asm volatile("s_waitcnt lgkmcnt(0)" ::: "memory"); \
                       __builtin_amdgcn_s_barrier(); } while (0)

__device__ __forceinline__ unsigned pk2(float lo, float hi) {
    unsigned r;
    asm("v_cvt_pk_bf16_f32 %0, %1, %2" : "=v"(r) : "v"(lo), "v"(hi));
    return r;
}
__device__ __forceinline__ ushort f2b(float f) {
    union { float f; unsigned u; } x; x.f = f;
    return (ushort)((x.u + 0x7FFFu + ((x.u >> 16) & 1u)) >> 16);
}
__device__ __forceinline__ float b2f(ushort h) {
    union { unsigned u; float f; } x; x.u = ((unsigned)h) << 16; return x.f;
}
__device__ __forceinline__ short8 ldfrag(const ushort* p) {
    return *reinterpret_cast<const short8*>(p);
}
__device__ __forceinline__ void st64(ushort* p, unsigned lo, unsigned hi) {
    unsigned long long v = ((unsigned long long)hi << 32) | (unsigned long long)lo;
    *reinterpret_cast<unsigned long long*>(p) = v;
}
__device__ __forceinline__ float wave_max(float v) {
#pragma unroll
    for (int off = 32; off > 0; off >>= 1) v = fmaxf(v, __shfl_xor(v, off, 64));
    return v;
}
__device__ __forceinline__ float blk_max(float v, float* scr, int tid) {
    v = wave_max(v);
    BARRIER();
    if ((tid & 63) == 0) scr[tid >> 6] = v;
    BARRIER();
    return fmaxf(fmaxf(scr[0], scr[1]), fmaxf(scr[2], scr[3]));
}
__device__ __forceinline__ short8 pk8(const float* v) {
    union { short8 s; unsigned u[4]; } r;
    r.u[0] = pk2(v[0], v[1]); r.u[1] = pk2(v[2], v[3]);
    r.u[2] = pk2(v[4], v[5]); r.u[3] = pk2(v[6], v[7]);
    return r.s;
}

// ======================= preconversion =======================
__global__ __launch_bounds__(256) void preconv(const float* __restrict__ mi,
                                               const float* __restrict__ mo,
                                               ushort* __restrict__ wsb) {
    __shared__ float lf[16384];
    const int tid = threadIdx.x, blk = blockIdx.x;
    if (blk < 127) {
        const float* src = mi + (size_t)blk * 8192;
#pragma unroll
        for (int n = 0; n < 8; n++)
            *reinterpret_cast<f32x4*>(lf + 4 * (tid + 256 * n)) =
                *reinterpret_cast<const f32x4*>(src + 4 * (tid + 256 * n));
        __syncthreads();
        ushort* d1 = wsb + MINB + (size_t)blk * 8192;   // [l][dd][i] straight
        ushort* d2 = wsb + MFIB + (size_t)blk * 8192;   // [m=(k,i)][d]
#pragma unroll
        for (int n = 0; n < 4; n++) {
            int c = tid + 256 * n;
            float va[8], vb[8];
            int m = c >> 3, d0 = (c & 7) * 8;
#pragma unroll
            for (int r = 0; r < 8; r++) {
                va[r] = lf[8 * c + r];
                vb[r] = lf[(d0 + r) * 128 + m];
            }
            *reinterpret_cast<short8*>(d1 + 8 * c) = pk8(va);
            *reinterpret_cast<short8*>(d2 + 8 * c) = pk8(vb);
        }
    } else {
        int s = blk - 127;
        const float* src = mo + (size_t)s * 16384;
#pragma unroll
        for (int n = 0; n < 16; n++)
            *reinterpret_cast<f32x4*>(lf + 4 * (tid + 256 * n)) =
                *reinterpret_cast<const f32x4*>(src + 4 * (tid + 256 * n));
        __syncthreads();
        ushort* d1 = wsb + MOTB + (size_t)s * 16384;    // [j][r][dd][i]
        ushort* d2 = wsb + MFOB + (size_t)s * 16384;    // [m=(k,ij)][d]
#pragma unroll
        for (int n = 0; n < 8; n++) {
            int c = tid + 256 * n;                      // short8 index in [0,2048)
            float va[8], vb[8];
            // FIXED indexing: 1024 short8 per j-slice; row (dd,i) = 128 u16 = 16 short8
            int j = c >> 10, r = (c >> 4) & 63, dg = c & 15;
            int m = c >> 3, d0 = (c & 7) * 8;
#pragma unroll
            for (int q = 0; q < 4; q++)
#pragma unroll
                for (int i = 0; i < 2; i++)
                    va[q * 2 + i] = lf[(dg * 4 + q) * 256 + r * 4 + i * 2 + j];
#pragma unroll
            for (int rr = 0; rr < 8; rr++) vb[rr] = lf[(d0 + rr) * 256 + m];
            *reinterpret_cast<short8*>(d1 + 8 * c) = pk8(va);
            *reinterpret_cast<short8*>(d2 + 8 * c) = pk8(vb);
        }
    }
}

// ======================= lognorm matmuls =======================
// MM1 (swapped): C1t[u][m] = sum_d Al[u][d]*MF[m][d]; T[k=(m/QW)][ (m%QW)*BS + u ] = C1t*sc
template <int QW>
__device__ __forceinline__ void ln_mm1(ushort* su, int q, int p, float sc, int tid) {
    constexpr int TSx = QW * BS + 8;
    constexpr int MW = 16 * QW;
    const int w = tid >> 6, g = (tid >> 4) & 3, l15 = tid & 15;
    const f32x4 fz = {0.f, 0.f, 0.f, 0.f};
    f32x4 acc[4][QW];
#pragma unroll
    for (int tr = 0; tr < 4; tr++)
#pragma unroll
        for (int tc = 0; tc < QW; tc++) acc[tr][tc] = fz;
#pragma unroll
    for (int ks = 0; ks < 2; ks++) {
        short8 bf[QW];
#pragma unroll
        for (int tc = 0; tc < QW; tc++)
            bf[tc] = ldfrag(su + L_MF(p) + (MW * w + 16 * tc + l15) * ST + 32 * ks + 8 * g);
#pragma unroll
        for (int tr = 0; tr < 4; tr++) {
            short8 af = ldfrag(su + L_AL(q) + (16 * tr + l15) * ST + 32 * ks + 8 * g);
#pragma unroll
            for (int tc = 0; tc < QW; tc++) acc[tr][tc] = MFMA16(af, bf[tc], acc[tr][tc]);
        }
    }
#pragma unroll
    for (int tr = 0; tr < 4; tr++)
#pragma unroll
        for (int tc = 0; tc < QW; tc++) {
            int m = MW * w + 16 * tc + l15;
            int k = m / QW, ij = m % QW, u0 = 16 * tr + 4 * g;
            st64(&su[L_T + k * TSx + ij * BS + u0],
                 pk2(acc[tr][tc][0] * sc, acc[tr][tc][1] * sc),
                 pk2(acc[tr][tc][2] * sc, acc[tr][tc][3] * sc));
        }
}
// MM2: S[k][l] = sum_{ij,u} T[k][ij*BS+u]*MF[l*QW+ij][u]; write Al(q^1) (symmetric store)
template <int QW>
__device__ __forceinline__ void ln_mm2(ushort* su, int q, int p, int tid, float* red) {
    constexpr int TSx = QW * BS + 8;
    const int w = tid >> 6, g = (tid >> 4) & 3, l15 = tid & 15;
    const f32x4 fz = {0.f, 0.f, 0.f, 0.f};
    f32x4 acc[4];
#pragma unroll
    for (int tc = 0; tc < 4; tc++) acc[tc] = fz;
#pragma unroll
    for (int ks2 = 0; ks2 < 2 * QW; ks2++) {
        short8 af = ldfrag(su + L_T + (16 * w + l15) * TSx + (ks2 >> 1) * BS + (ks2 & 1) * 32 + 8 * g);
#pragma unroll
        for (int tc = 0; tc < 4; tc++) {
            short8 bf = ldfrag(su + L_MF(p) + ((16 * tc + l15) * QW + (ks2 >> 1)) * ST +
                               (ks2 & 1) * 32 + 8 * g);
            acc[tc] = MFMA16(af, bf, acc[tc]);
        }
    }
    float lm = 0.f;
#pragma unroll
    for (int tc = 0; tc < 4; tc++)
#pragma unroll
        for (int r2 = 0; r2 < 4; r2++) lm = fmaxf(lm, fabsf(acc[tc][r2]));
    lm = wave_max(lm);
    if ((tid & 63) == 0) red[w] = lm;
#pragma unroll
    for (int tc = 0; tc < 4; tc++)
        st64(&su[L_AL(q ^ 1) + (16 * tc + l15) * ST + 16 * w + 4 * g],
             pk2(acc[tc][0], acc[tc][1]), pk2(acc[tc][2], acc[tc][3]));
}
// fp32 fallback staging of MF[m][d]
template <int QWN>
__device__ __forceinline__ void ln_stage_raw(ushort* su, int pn, const float* __restrict__ Mg, int tid) {
    const int a63 = tid & 63, hi = tid >> 6;
#pragma unroll
    for (int n = 0; n < 4 * QWN; n++) {
        int m = hi + 4 * n;
        f32x4 v = *reinterpret_cast<const f32x4*>(Mg + 4 * ((size_t)a63 * (16 * QWN) + m));
#pragma unroll
        for (int c = 0; c < 4; c++) su[L_MF(pn) + (4 * m + c) * ST + a63] = f2b(v[c]);
    }
}

// ======================= batch matmuls =======================
__device__ __forceinline__ void bt_mm1(ushort* su, int bb, int tid) {
    const int w = tid >> 6, g = (tid >> 4) & 3, l15 = tid & 15;
    const f32x4 fz = {0.f, 0.f, 0.f, 0.f};
    f32x4 acc[2][4];
#pragma unroll
    for (int j = 0; j < 2; j++)
#pragma unroll
        for (int tr = 0; tr < 4; tr++) acc[j][tr] = fz;
#pragma unroll
    for (int ks = 0; ks < 2; ks++) {
        short8 q0 = ldfrag(su + BPL(bb, 1) + (16 * w + l15) * ST + 32 * ks + 8 * g);
        short8 q1 = ldfrag(su + BPL(bb, 2) + (16 * w + l15) * ST + 32 * ks + 8 * g);
#pragma unroll
        for (int tr = 0; tr < 4; tr++) {
            short8 pA = ldfrag(su + BPL(bb, 0) + (16 * tr + l15) * ST + 32 * ks + 8 * g);
            acc[0][tr] = MFMA16(pA, q0, acc[0][tr]);
            acc[1][tr] = MFMA16(pA, q1, acc[1][tr]);
        }
    }
#pragma unroll
    for (int j = 0; j < 2; j++)
#pragma unroll
        for (int tr = 0; tr < 4; tr++)
            st64(&su[BPL(bb, 3 + j) + (16 * w + l15) * ST + 16 * tr + 4 * g],
                 pk2(acc[j][tr][0], acc[j][tr][1]), pk2(acc[j][tr][2], acc[j][tr][3]));
}
__device__ __forceinline__ void bt_mm2(ushort* su, int bb, float sc, int tid) {
    const int w = tid >> 6, g = (tid >> 4) & 3, l15 = tid & 15;
    const f32x4 fz = {0.f, 0.f, 0.f, 0.f};
    f32x4 acc[2][4];
#pragma unroll
    for (int j = 0; j < 2; j++)
#pragma unroll
        for (int tr = 0; tr < 4; tr++) acc[j][tr] = fz;
#pragma unroll
    for (int ks = 0; ks < 2; ks++) {
        short8 q0 = ldfrag(su + BPL(bb, 3) + (16 * w + l15) * ST + 32 * ks + 8 * g);
        short8 q1 = ldfrag(su + BPL(bb, 4) + (16 * w + l15) * ST + 32 * ks + 8 * g);
#pragma unroll
        for (int tr = 0; tr < 4; tr++) {
            short8 pA = ldfrag(su + BPL(bb, 7) + (16 * tr + l15) * ST + 32 * ks + 8 * g);
            acc[0][tr] = MFMA16(pA, q0, acc[0][tr]);
            acc[1][tr] = MFMA16(pA, q1, acc[1][tr]);
        }
    }
#pragma unroll
    for (int j = 0; j < 2; j++)
#pragma unroll
        for (int tr = 0; tr < 4; tr++)
            st64(&su[BPL(bb, 5 + j) + (16 * w + l15) * ST + 16 * tr + 4 * g],
                 pk2(acc[j][tr][0] * sc, acc[j][tr][1] * sc),
                 pk2(acc[j][tr][2] * sc, acc[j][tr][3] * sc));
}
__device__ __forceinline__ void bt_mm3(ushort* su, int bb, int tid, float* redw) {
    const int w = tid >> 6, g = (tid >> 4) & 3, l15 = tid & 15;
    const f32x4 fz = {0.f, 0.f, 0.f, 0.f};
    f32x4 acc[4];
#pragma unroll
    for (int tc = 0; tc < 4; tc++) acc[tc] = fz;
#pragma unroll
    for (int j = 0; j < 2; j++)
#pragma unroll
        for (int ks = 0; ks < 2; ks++) {
            short8 pT = ldfrag(su + BPL(bb, 5 + j) + (16 * w + l15) * ST + 32 * ks + 8 * g);
#pragma unroll
            for (int tc = 0; tc < 4; tc++) {
                short8 qf = ldfrag(su + BPL(bb, 3 + j) + (16 * tc + l15) * ST + 32 * ks + 8 * g);
                acc[tc] = MFMA16(pT, qf, acc[tc]);
            }
        }
    float lm = 0.f;
#pragma unroll
    for (int tc = 0; tc < 4; tc++)
#pragma unroll
        for (int r2 = 0; r2 < 4; r2++) lm = fmaxf(lm, fabsf(acc[tc][r2]));
    lm = wave_max(lm);
    if ((tid & 63) == 0) redw[w] = lm;
#pragma unroll
    for (int tc = 0; tc < 4; tc++)
        st64(&su[BPL(bb, 7) + (16 * tc + l15) * ST + 16 * w + 4 * g],
             pk2(acc[tc][0], acc[tc][1]), pk2(acc[tc][2], acc[tc][3]));
}

// ======================= main chain kernel =======================
template <bool BFS>
__global__ __launch_bounds__(256, 1) void proj_chain(
    const float* __restrict__ inp, const float* __restrict__ mps_in,
    const float* __restrict__ mps_out, float* __restrict__ wsf,
    const ushort* __restrict__ wsb) {
    __shared__ __align__(16) ushort su[SU_U16];
    __shared__ float fsc[176];
    float* red = fsc;          // [2][2][4]: rb*8 + bb*4 + w
    float* bms = fsc + 16;     // blk_max scratch [4]
    float* A0s = fsc + 32;     // [128]
    const int tid = threadIdx.x;

    if (blockIdx.x == 32) {
        // ================= _log_norm chain =================
#pragma unroll
        for (int n = 0; n < 9; n++)
            reinterpret_cast<unsigned*>(su)[tid + 256 * n] = 0u;
        if (tid == 0) su[0] = (ushort)0x3F80;
        short8 pf[8];
        if constexpr (BFS) {
            // stage site 0 (QW=4) from MFoB
#pragma unroll
            for (int n = 0; n < 8; n++) {
                int c = tid + 256 * n;
                *reinterpret_cast<short8*>(su + L_MF(0) + (c >> 3) * ST + (c & 7) * 8) =
                    *reinterpret_cast<const short8*>(wsb + MFOB + (size_t)c * 8);
            }
            // prefetch site 1 (QW=2)
#pragma unroll
            for (int n = 0; n < 8; n++)
                if (n < 4)
                    pf[n] = *reinterpret_cast<const short8*>(wsb + MFIB + (size_t)(tid + 256 * n) * 8);
        } else {
            ln_stage_raw<4>(su, 0, mps_out, tid);
        }
        BARRIER();
        float accl = 0.f;
        for (int i = 0; i < 256; i++) {
            int p = i & 1;
            int qw = (((i & 1) == 0) || i == 255) ? 4 : 2;
            float sc = 1.f;
            if (i > 0) {
                float* rb = red + (i & 1) * 8;
                float m4 = fmaxf(fmaxf(rb[0], rb[1]), fmaxf(rb[2], rb[3]));
                sc = 1.f / m4;
                if (tid == 0) accl += logf(m4);
            }
            if (qw == 4) ln_mm1<4>(su, p, p, sc, tid);
            else         ln_mm1<2>(su, p, p, sc, tid);
            if (i + 1 < 256) {
                int j = i + 1;
                int qn = (((j & 1) == 0) || j == 255) ? 4 : 2;
                if constexpr (BFS) {
#pragma unroll
                    for (int n = 0; n < 8; n++)
                        if (n < 2 * qn) {
                            int c = tid + 256 * n;
                            *reinterpret_cast<short8*>(su + L_MF(p ^ 1) + (c >> 3) * ST + (c & 7) * 8) = pf[n];
                        }
                } else {
                    if (qn == 4)
                        ln_stage_raw<4>(su, p ^ 1,
                                        mps_out + (size_t)16384 * ((j == 255) ? 128 : (j >> 1)), tid);
                    else
                        ln_stage_raw<2>(su, p ^ 1, mps_in + (size_t)8192 * (j >> 1), tid);
                }
            }
            if constexpr (BFS) {
                int j2 = i + 2;
                if (j2 < 256) {
                    int qn2 = (((j2 & 1) == 0) || j2 == 255) ? 4 : 2;
                    const ushort* src = (qn2 == 4)
                        ? wsb + MFOB + 16384ull * (unsigned)((j2 == 255) ? 128 : (j2 >> 1))
                        : wsb + MFIB + 8192ull * (unsigned)(j2 >> 1);
#pragma unroll
                    for (int n = 0; n < 8; n++)
                        if (n < 2 * qn2)
                            pf[n] = *reinterpret_cast<const short8*>(src + (size_t)(tid + 256 * n) * 8);
                }
            }
            if (qw == 4) ln_mm2<4>(su, p, p, tid, red + ((i + 1) & 1) * 8);
            else         ln_mm2<2>(su, p, p, tid, red + ((i + 1) & 1) * 8);
            BARRIER();
        }
        if (tid == 0) { accl += logf(b2f(su[L_AL(0)])); wsf[64] = accl; }
        return;
    }

    // ================= batched <psi|psi> chain (2 per block) =================
    const int b0 = blockIdx.x * 2;
    float accl0 = 0.f, accl1 = 0.f;
    short8 pfA[4], pfX[8];

    auto loadpf = [&](int k2) {
        const ushort* mb = wsb + MINB + (size_t)(k2 - 1) * 8192;
        const ushort* xb = wsb + MOTB + (size_t)k2 * 16384;
#pragma unroll
        for (int n = 0; n < 4; n++)
            pfA[n] = *reinterpret_cast<const short8*>(mb + (size_t)(tid + 256 * n) * 8);
#pragma unroll
        for (int n = 0; n < 8; n++)
            pfX[n] = *reinterpret_cast<const short8*>(xb + (size_t)((n >> 2) * 1024 + tid + 256 * (n & 3)) * 8);
    };
    auto stage_bf = [&](int bb, int k2) {
        int b = b0 + bb;
        float jv0 = inp[((2 * k2 - 1) * 64 + b) * 2], jv1 = inp[((2 * k2 - 1) * 64 + b) * 2 + 1];
        float ov0 = inp[((2 * k2) * 64 + b) * 2],     ov1 = inp[((2 * k2) * 64 + b) * 2 + 1];
#pragma unroll
        for (int n = 0; n < 4; n++) {
            int c = tid + 256 * n, l = c >> 4, dd0 = (c & 15) * 4;
            short8 r8 = pfA[n];
            float v0 = jv0 * b2f((ushort)r8[0]) + jv1 * b2f((ushort)r8[1]);
            float v1 = jv0 * b2f((ushort)r8[2]) + jv1 * b2f((ushort)r8[3]);
            float v2 = jv0 * b2f((ushort)r8[4]) + jv1 * b2f((ushort)r8[5]);
            float v3 = jv0 * b2f((ushort)r8[6]) + jv1 * b2f((ushort)r8[7]);
            st64(&su[BPL(bb, 0) + l * ST + dd0], pk2(v0, v1), pk2(v2, v3));
        }
#pragma unroll
        for (int n = 0; n < 8; n++) {
            // FIXED: row (dd,i) = 128 u16 = 16 short8 -> r = c>>4, dd-group = c&15
            int j = n >> 2, c = tid + 256 * (n & 3), r = c >> 4, dd0 = (c & 15) * 4;
            short8 r8 = pfX[n];
            float v0 = ov0 * b2f((ushort)r8[0]) + ov1 * b2f((ushort)r8[1]);
            float v1 = ov0 * b2f((ushort)r8[2]) + ov1 * b2f((ushort)r8[3]);
            float v2 = ov0 * b2f((ushort)r8[4]) + ov1 * b2f((ushort)r8[5]);
            float v3 = ov0 * b2f((ushort)r8[6]) + ov1 * b2f((ushort)r8[7]);
            st64(&su[BPL(bb, 1 + j) + r * ST + dd0], pk2(v0, v1), pk2(v2, v3));
        }
    };
    auto stage_f32 = [&](int bb, int k2) {
        int b = b0 + bb;
        const int a63 = tid & 63, hi2 = tid >> 6;
        const float* Min = mps_in + (size_t)(k2 - 1) * 8192;
        const float* Mo  = mps_out + (size_t)k2 * 16384;
        float jv0 = inp[((2 * k2 - 1) * 64 + b) * 2], jv1 = inp[((2 * k2 - 1) * 64 + b) * 2 + 1];
        float ov0 = inp[((2 * k2) * 64 + b) * 2],     ov1 = inp[((2 * k2) * 64 + b) * 2 + 1];
#pragma unroll
        for (int n = 0; n < 8; n++) {
            int f = tid + 256 * n, l = f >> 5, dd = (2 * f) & 63;
            f32x4 v = *reinterpret_cast<const f32x4*>(Min + 4 * f);
            *reinterpret_cast<unsigned*>(&su[BPL(bb, 0) + l * ST + dd]) =
                pk2(jv0 * v[0] + jv1 * v[1], jv0 * v[2] + jv1 * v[3]);
        }
#pragma unroll
        for (int n = 0; n < 16; n++) {
            int r = hi2 + 4 * n;
            f32x4 v = *reinterpret_cast<const f32x4*>(Mo + 4 * ((size_t)a63 * 64 + r));
            su[BPL(bb, 1) + r * ST + a63] = f2b(ov0 * v[0] + ov1 * v[2]);
            su[BPL(bb, 2) + r * ST + a63] = f2b(ov0 * v[1] + ov1 * v[3]);
        }
    };

    if constexpr (BFS) loadpf(1);
    // ---- site 0 per chain ----
#pragma unroll
    for (int bb = 0; bb < 2; bb++) {
        int b = b0 + bb;
        float iv0 = inp[b * 2 + 0], iv1 = inp[b * 2 + 1];
        if (tid < 128) {
            int r = tid >> 1, jj = tid & 1;
            A0s[tid] = iv0 * mps_out[r * 4 + jj] + iv1 * mps_out[r * 4 + 2 + jj];
        }
        BARRIER();
        float vals[16];
        float lm = 0.f;
#pragma unroll
        for (int n = 0; n < 16; n++) {
            int e = tid + 256 * n;
            int u = e >> 6, d2 = e & 63;
            float v = A0s[2 * u] * A0s[2 * d2] + A0s[2 * u + 1] * A0s[2 * d2 + 1];
            vals[n] = v;
            lm = fmaxf(lm, fabsf(v));
        }
        float amax = blk_max(lm, bms, tid);
        if (tid == 0) { if (bb == 0) accl0 += logf(amax); else accl1 += logf(amax); }
        float sc0 = (amax > 0.f) ? 1.f / amax : 0.f;
#pragma unroll
        for (int n = 0; n < 16; n++) {
            int e = tid + 256 * n;
            su[BPL(bb, 7) + (e >> 6) * ST + (e & 63)] = f2b(vals[n] * sc0);
        }
        BARRIER();
    }
    if (tid < 8) red[8 + tid] = 1.0f;   // rb=1 entries for k=1
    if constexpr (BFS) {
        stage_bf(0, 1); stage_bf(1, 1);
        loadpf(2);
    } else {
        stage_f32(0, 1); stage_f32(1, 1);
    }
    BARRIER();

    for (int k = 1; k <= 127; k++) {
        int rb = k & 1;
        bt_mm1(su, 0, tid);
        bt_mm1(su, 1, tid);
#pragma unroll
        for (int bb = 0; bb < 2; bb++) {
            float* r4 = red + rb * 8 + bb * 4;
            float m4 = fmaxf(fmaxf(r4[0], r4[1]), fmaxf(r4[2], r4[3]));
            float sc = 1.f / m4;
            if (tid == 0) { if (bb == 0) accl0 += logf(m4); else accl1 += logf(m4); }
            bt_mm2(su, bb, sc, tid);
        }
        BARRIER();  // B1: A_jT now visible block-wide; T_j wave-local
        if (k < 127) {
            if constexpr (BFS) { stage_bf(0, k + 1); stage_bf(1, k + 1); }
            else               { stage_f32(0, k + 1); stage_f32(1, k + 1); }
        }
        bt_mm3(su, 0, tid, red + ((rb ^ 1) * 8 + 0));
        bt_mm3(su, 1, tid, red + ((rb ^ 1) * 8 + 4));
        if constexpr (BFS) { if (k < 126) loadpf(k + 2); }
        BARRIER();  // B2: Al + staged site visible
    }

    // ---- final site i=255 per chain ----
    const float* Mo128 = mps_out + (size_t)128 * 16384;
#pragma unroll
    for (int bb = 0; bb < 2; bb++) {
        int b = b0 + bb;
        float fv0 = inp[(255 * 64 + b) * 2], fv1 = inp[(255 * 64 + b) * 2 + 1];
        if (tid < 128) {
            int d2 = tid >> 1, jj = tid & 1;
            A0s[tid] = fv0 * Mo128[d2 * 256 + jj] + fv1 * Mo128[d2 * 256 + 2 + jj];
        }
        BARRIER();
        float part = 0.f;
#pragma unroll
        for (int n = 0; n < 16; n++) {
            int e = tid + 256 * n;
            int d2 = e >> 6, u = e & 63;
            part += b2f(su[BPL(bb, 7) + d2 * ST + u]) *
                    (A0s[2 * d2] * A0s[2 * u] + A0s[2 * d2 + 1] * A0s[2 * u + 1]);
        }
#pragma unroll
        for (int off = 32; off > 0; off >>= 1)
            part += __shfl_xor(part, off, 64);
        BARRIER();
        if ((tid & 63) == 0) bms[tid >> 6] = part;
        BARRIER();
        if (tid == 0) {
            float v = bms[0] + bms[1] + bms[2] + bms[3];
            wsf[b] = (bb == 0 ? accl0 : accl1) + logf(fabsf(v));
        }
        BARRIER();
    }
}

__global__ void proj_combine(const float* __restrict__ ws, float* __restrict__ out, int n) {
    int t = threadIdx.x;
    if (t < n) out[t] = ws[t] - ws[64];
}

extern "C" void kernel_launch(void* const* d_in, const int* in_sizes, int n_in,
                              void* d_out, int out_size, void* d_ws, size_t ws_size,
                              hipStream_t stream) {
    const float* inp = (const float*)d_in[0];
    const float* mi  = (const float*)d_in[1];
    const float* mo  = (const float*)d_in[2];
    float* wsf = (float*)d_ws;
    ushort* wsb = (ushort*)((char*)d_ws + 512);
    size_t need = 512 + WS_U16_TOT * 2;
    if (ws_size >= need) {
        preconv<<<dim3(256), dim3(256), 0, stream>>>(mi, mo, wsb);
        proj_chain<true><<<dim3(33), dim3(256), 0, stream>>>(inp, mi, mo, wsf, wsb);
    } else {
        proj_chain<false><<<dim3(33), dim3(256), 0, stream>>>(inp, mi, mo, wsf, wsb);
    }
    proj_combine<<<dim3(1), dim3(64), 0, stream>>>(wsf, (float*)d_out, out_size);
}

// Round 6
// 475.079 us; speedup vs baseline: 10.2082x; 1.3112x over previous
//
#include <hip/hip_runtime.h>
#include <math.h>

// Projector MPS chain, N=256, S=2, D=64, d=2, B=64, NOUT=129, NIN=127.
// Round 6: MF row-permutation (row' = ij*64+k) kills MM2 8-way bank conflict;
// 1 batch chain per block (blocks 0..63), block 64 = lognorm chain.

typedef __attribute__((ext_vector_type(8))) short short8;   // 8 bf16
typedef __attribute__((ext_vector_type(4))) float f32x4;

#define MFMA16(a, b, c) __builtin_amdgcn_mfma_f32_16x16x32_bf16(a, b, c, 0, 0, 0)

#define ST 72          // row stride (u16), 144 B rows
#define PL 4608        // 64*ST plane
#define BS 72          // lognorm T: ij-block stride
// lognorm LDS map (u16)
#define L_AL(q) ((q) * PL)                 // 2 planes
#define L_MF(p) (2 * PL + (p) * 18432)     // 2 x [256 rows'][72]
#define L_T     (2 * PL + 2 * 18432)       // [64][296] max = 18944
#define SU_U16  65024                      // 130048 B
// batch LDS map (single batch): planes 0 AIN,1 X0,2 X1,3 A0T,4 A1T,5 T0,6 T1,7 AL
#define BPL(i) ((i) * PL)

// ws u16 offsets (after 512-byte header holding ws[65] f32 results)
#define MINB 0ull
#define MOTB 1040384ull
#define MFIB 3153920ull
#define MFOB 4194304ull
#define WS_U16_TOT 6307840ull

#define BARRIER() do { asm volatile("s_waitcnt lgkmcnt(0)" ::: "memory"); \
                       __builtin_amdgcn_s_barrier(); } while (0)

__device__ __forceinline__ unsigned pk2(float lo, float hi) {
    unsigned r;
    asm("v_cvt_pk_bf16_f32 %0, %1, %2" : "=v"(r) : "v"(lo), "v"(hi));
    return r;
}
__device__ __forceinline__ ushort f2b(float f) {
    union { float f; unsigned u; } x; x.f = f;
    return (ushort)((x.u + 0x7FFFu + ((x.u >> 16) & 1u)) >> 16);
}
__device__ __forceinline__ float b2f(ushort h) {
    union { unsigned u; float f; } x; x.u = ((unsigned)h) << 16; return x.f;
}
__device__ __forceinline__ short8 ldfrag(const ushort* p) {
    return *reinterpret_cast<const short8*>(p);
}
__device__ __forceinline__ void st64(ushort* p, unsigned lo, unsigned hi) {
    unsigned long long v = ((unsigned long long)hi << 32) | (unsigned long long)lo;
    *reinterpret_cast<unsigned long long*>(p) = v;
}
__device__ __forceinline__ float wave_max(float v) {
#pragma unroll
    for (int off = 32; off > 0; off >>= 1) v = fmaxf(v, __shfl_xor(v, off, 64));
    return v;
}
__device__ __forceinline__ float blk_max(float v, float* scr, int tid) {
    v = wave_max(v);
    BARRIER();
    if ((tid & 63) == 0) scr[tid >> 6] = v;
    BARRIER();
    return fmaxf(fmaxf(scr[0], scr[1]), fmaxf(scr[2], scr[3]));
}
__device__ __forceinline__ short8 pk8(const float* v) {
    union { short8 s; unsigned u[4]; } r;
    r.u[0] = pk2(v[0], v[1]); r.u[1] = pk2(v[2], v[3]);
    r.u[2] = pk2(v[4], v[5]); r.u[3] = pk2(v[6], v[7]);
    return r.s;
}

// ======================= preconversion =======================
// MF layouts (MFIB/MFOB) are stored in PERMUTED row order: row' = ij*64 + k
// (source column m = k*QW + ij), so MM2's B-reads are bank-conflict-free.
__global__ __launch_bounds__(256) void preconv(const float* __restrict__ mi,
                                               const float* __restrict__ mo,
                                               ushort* __restrict__ wsb) {
    __shared__ float lf[16384];
    const int tid = threadIdx.x, blk = blockIdx.x;
    if (blk < 127) {
        const float* src = mi + (size_t)blk * 8192;
#pragma unroll
        for (int n = 0; n < 8; n++)
            *reinterpret_cast<f32x4*>(lf + 4 * (tid + 256 * n)) =
                *reinterpret_cast<const f32x4*>(src + 4 * (tid + 256 * n));
        __syncthreads();
        ushort* d1 = wsb + MINB + (size_t)blk * 8192;   // [l][dd][i] straight
        ushort* d2 = wsb + MFIB + (size_t)blk * 8192;   // [row'=i*64+k][d]
#pragma unroll
        for (int n = 0; n < 4; n++) {
            int c = tid + 256 * n;
            float va[8], vb[8];
            int rp = c >> 3, d0 = (c & 7) * 8;
            int msrc = (rp & 63) * 2 + (rp >> 6);       // m = k*2 + i
#pragma unroll
            for (int r = 0; r < 8; r++) {
                va[r] = lf[8 * c + r];
                vb[r] = lf[(d0 + r) * 128 + msrc];
            }
            *reinterpret_cast<short8*>(d1 + 8 * c) = pk8(va);
            *reinterpret_cast<short8*>(d2 + 8 * c) = pk8(vb);
        }
    } else {
        int s = blk - 127;
        const float* src = mo + (size_t)s * 16384;
#pragma unroll
        for (int n = 0; n < 16; n++)
            *reinterpret_cast<f32x4*>(lf + 4 * (tid + 256 * n)) =
                *reinterpret_cast<const f32x4*>(src + 4 * (tid + 256 * n));
        __syncthreads();
        ushort* d1 = wsb + MOTB + (size_t)s * 16384;    // [j][r][dd][i]
        ushort* d2 = wsb + MFOB + (size_t)s * 16384;    // [row'=ij*64+k][d]
#pragma unroll
        for (int n = 0; n < 8; n++) {
            int c = tid + 256 * n;                      // short8 index in [0,2048)
            float va[8], vb[8];
            int j = c >> 10, r = (c >> 4) & 63, dg = c & 15;
            int rp = c >> 3, d0 = (c & 7) * 8;
            int msrc = (rp & 63) * 4 + (rp >> 6);       // m = k*4 + ij
#pragma unroll
            for (int q = 0; q < 4; q++)
#pragma unroll
                for (int i = 0; i < 2; i++)
                    va[q * 2 + i] = lf[(dg * 4 + q) * 256 + r * 4 + i * 2 + j];
#pragma unroll
            for (int rr = 0; rr < 8; rr++) vb[rr] = lf[(d0 + rr) * 256 + msrc];
            *reinterpret_cast<short8*>(d1 + 8 * c) = pk8(va);
            *reinterpret_cast<short8*>(d2 + 8 * c) = pk8(vb);
        }
    }
}

// ======================= lognorm matmuls =======================
// MM1 (swapped): C1t[u][m'] = sum_d Al[u][d]*MFp[m'][d], wave w covers
// m' in {64*tc + 16*w + l15} (tc = ij) -> T[k=16w+l15][ij*BS + u] wave-local.
template <int QW>
__device__ __forceinline__ void ln_mm1(ushort* su, int q, int p, float sc, int tid) {
    constexpr int TSx = QW * BS + 8;
    const int w = tid >> 6, g = (tid >> 4) & 3, l15 = tid & 15;
    const f32x4 fz = {0.f, 0.f, 0.f, 0.f};
    f32x4 acc[4][QW];
#pragma unroll
    for (int tr = 0; tr < 4; tr++)
#pragma unroll
        for (int tc = 0; tc < QW; tc++) acc[tr][tc] = fz;
#pragma unroll
    for (int ks = 0; ks < 2; ks++) {
        short8 bf[QW];
#pragma unroll
        for (int tc = 0; tc < QW; tc++)
            bf[tc] = ldfrag(su + L_MF(p) + (64 * tc + 16 * w + l15) * ST + 32 * ks + 8 * g);
#pragma unroll
        for (int tr = 0; tr < 4; tr++) {
            short8 af = ldfrag(su + L_AL(q) + (16 * tr + l15) * ST + 32 * ks + 8 * g);
#pragma unroll
            for (int tc = 0; tc < QW; tc++) acc[tr][tc] = MFMA16(af, bf[tc], acc[tr][tc]);
        }
    }
#pragma unroll
    for (int tr = 0; tr < 4; tr++)
#pragma unroll
        for (int tc = 0; tc < QW; tc++)
            st64(&su[L_T + (16 * w + l15) * TSx + tc * BS + 16 * tr + 4 * g],
                 pk2(acc[tr][tc][0] * sc, acc[tr][tc][1] * sc),
                 pk2(acc[tr][tc][2] * sc, acc[tr][tc][3] * sc));
}
// MM2: S[k][l] = sum_{ij,u} T[k][ij*BS+u] * MFp[ij*64+l][u]; write Al(q^1) (symmetric)
template <int QW>
__device__ __forceinline__ void ln_mm2(ushort* su, int q, int p, int tid, float* red) {
    constexpr int TSx = QW * BS + 8;
    const int w = tid >> 6, g = (tid >> 4) & 3, l15 = tid & 15;
    const f32x4 fz = {0.f, 0.f, 0.f, 0.f};
    f32x4 acc[4];
#pragma unroll
    for (int tc = 0; tc < 4; tc++) acc[tc] = fz;
#pragma unroll
    for (int ks2 = 0; ks2 < 2 * QW; ks2++) {
        short8 af = ldfrag(su + L_T + (16 * w + l15) * TSx + (ks2 >> 1) * BS + (ks2 & 1) * 32 + 8 * g);
#pragma unroll
        for (int tc = 0; tc < 4; tc++) {
            short8 bf = ldfrag(su + L_MF(p) + (((ks2 >> 1) << 6) + 16 * tc + l15) * ST +
                               (ks2 & 1) * 32 + 8 * g);
            acc[tc] = MFMA16(af, bf, acc[tc]);
        }
    }
    float lm = 0.f;
#pragma unroll
    for (int tc = 0; tc < 4; tc++)
#pragma unroll
        for (int r2 = 0; r2 < 4; r2++) lm = fmaxf(lm, fabsf(acc[tc][r2]));
    lm = wave_max(lm);
    if ((tid & 63) == 0) red[w] = lm;
#pragma unroll
    for (int tc = 0; tc < 4; tc++)
        st64(&su[L_AL(q ^ 1) + (16 * tc + l15) * ST + 16 * w + 4 * g],
             pk2(acc[tc][0], acc[tc][1]), pk2(acc[tc][2], acc[tc][3]));
}
// fp32 fallback staging of MFp (permuted rows)
template <int QWN>
__device__ __forceinline__ void ln_stage_raw(ushort* su, int pn, const float* __restrict__ Mg, int tid) {
    const int a63 = tid & 63, hi = tid >> 6;
#pragma unroll
    for (int n = 0; n < 4 * QWN; n++) {
        int mb = hi + 4 * n;
        f32x4 v = *reinterpret_cast<const f32x4*>(Mg + 4 * ((size_t)a63 * (16 * QWN) + mb));
#pragma unroll
        for (int c = 0; c < 4; c++) {
            int m = 4 * mb + c;
            int rp = (m & (QWN - 1)) * 64 + (m / QWN);
            su[L_MF(pn) + rp * ST + a63] = f2b(v[c]);
        }
    }
}

// ======================= batch matmuls (single chain) =======================
__device__ __forceinline__ void bt_mm1(ushort* su, int tid) {
    const int w = tid >> 6, g = (tid >> 4) & 3, l15 = tid & 15;
    const f32x4 fz = {0.f, 0.f, 0.f, 0.f};
    f32x4 acc[2][4];
#pragma unroll
    for (int j = 0; j < 2; j++)
#pragma unroll
        for (int tr = 0; tr < 4; tr++) acc[j][tr] = fz;
#pragma unroll
    for (int ks = 0; ks < 2; ks++) {
        short8 q0 = ldfrag(su + BPL(1) + (16 * w + l15) * ST + 32 * ks + 8 * g);
        short8 q1 = ldfrag(su + BPL(2) + (16 * w + l15) * ST + 32 * ks + 8 * g);
#pragma unroll
        for (int tr = 0; tr < 4; tr++) {
            short8 pA = ldfrag(su + BPL(0) + (16 * tr + l15) * ST + 32 * ks + 8 * g);
            acc[0][tr] = MFMA16(pA, q0, acc[0][tr]);
            acc[1][tr] = MFMA16(pA, q1, acc[1][tr]);
        }
    }
#pragma unroll
    for (int j = 0; j < 2; j++)
#pragma unroll
        for (int tr = 0; tr < 4; tr++)
            st64(&su[BPL(3 + j) + (16 * w + l15) * ST + 16 * tr + 4 * g],
                 pk2(acc[j][tr][0], acc[j][tr][1]), pk2(acc[j][tr][2], acc[j][tr][3]));
}
__device__ __forceinline__ void bt_mm2(ushort* su, float sc, int tid) {
    const int w = tid >> 6, g = (tid >> 4) & 3, l15 = tid & 15;
    const f32x4 fz = {0.f, 0.f, 0.f, 0.f};
    f32x4 acc[2][4];
#pragma unroll
    for (int j = 0; j < 2; j++)
#pragma unroll
        for (int tr = 0; tr < 4; tr++) acc[j][tr] = fz;
#pragma unroll
    for (int ks = 0; ks < 2; ks++) {
        short8 q0 = ldfrag(su + BPL(3) + (16 * w + l15) * ST + 32 * ks + 8 * g);
        short8 q1 = ldfrag(su + BPL(4) + (16 * w + l15) * ST + 32 * ks + 8 * g);
#pragma unroll
        for (int tr = 0; tr < 4; tr++) {
            short8 pA = ldfrag(su + BPL(7) + (16 * tr + l15) * ST + 32 * ks + 8 * g);
            acc[0][tr] = MFMA16(pA, q0, acc[0][tr]);
            acc[1][tr] = MFMA16(pA, q1, acc[1][tr]);
        }
    }
#pragma unroll
    for (int j = 0; j < 2; j++)
#pragma unroll
        for (int tr = 0; tr < 4; tr++)
            st64(&su[BPL(5 + j) + (16 * w + l15) * ST + 16 * tr + 4 * g],
                 pk2(acc[j][tr][0] * sc, acc[j][tr][1] * sc),
                 pk2(acc[j][tr][2] * sc, acc[j][tr][3] * sc));
}
__device__ __forceinline__ void bt_mm3(ushort* su, int tid, float* redw) {
    const int w = tid >> 6, g = (tid >> 4) & 3, l15 = tid & 15;
    const f32x4 fz = {0.f, 0.f, 0.f, 0.f};
    f32x4 acc[4];
#pragma unroll
    for (int tc = 0; tc < 4; tc++) acc[tc] = fz;
#pragma unroll
    for (int j = 0; j < 2; j++)
#pragma unroll
        for (int ks = 0; ks < 2; ks++) {
            short8 pT = ldfrag(su + BPL(5 + j) + (16 * w + l15) * ST + 32 * ks + 8 * g);
#pragma unroll
            for (int tc = 0; tc < 4; tc++) {
                short8 qf = ldfrag(su + BPL(3 + j) + (16 * tc + l15) * ST + 32 * ks + 8 * g);
                acc[tc] = MFMA16(pT, qf, acc[tc]);
            }
        }
    float lm = 0.f;
#pragma unroll
    for (int tc = 0; tc < 4; tc++)
#pragma unroll
        for (int r2 = 0; r2 < 4; r2++) lm = fmaxf(lm, fabsf(acc[tc][r2]));
    lm = wave_max(lm);
    if ((tid & 63) == 0) redw[w] = lm;
#pragma unroll
    for (int tc = 0; tc < 4; tc++)
        st64(&su[BPL(7) + (16 * tc + l15) * ST + 16 * w + 4 * g],
             pk2(acc[tc][0], acc[tc][1]), pk2(acc[tc][2], acc[tc][3]));
}

// ======================= main chain kernel =======================
template <bool BFS>
__global__ __launch_bounds__(256, 1) void proj_chain(
    const float* __restrict__ inp, const float* __restrict__ mps_in,
    const float* __restrict__ mps_out, float* __restrict__ wsf,
    const ushort* __restrict__ wsb) {
    __shared__ __align__(16) ushort su[SU_U16];
    __shared__ float fsc[176];
    float* red = fsc;          // batch: [2][4] rb*4+w ; lognorm: [2][..] (i&1)*8+w
    float* bms = fsc + 16;     // blk_max scratch [4]
    float* A0s = fsc + 32;     // [128]
    const int tid = threadIdx.x;

    if (blockIdx.x == 64) {
        // ================= _log_norm chain =================
#pragma unroll
        for (int n = 0; n < 9; n++)
            reinterpret_cast<unsigned*>(su)[tid + 256 * n] = 0u;
        if (tid == 0) su[0] = (ushort)0x3F80;
        short8 pf[8];
        if constexpr (BFS) {
#pragma unroll
            for (int n = 0; n < 8; n++) {
                int c = tid + 256 * n;
                *reinterpret_cast<short8*>(su + L_MF(0) + (c >> 3) * ST + (c & 7) * 8) =
                    *reinterpret_cast<const short8*>(wsb + MFOB + (size_t)c * 8);
            }
#pragma unroll
            for (int n = 0; n < 8; n++)
                if (n < 4)
                    pf[n] = *reinterpret_cast<const short8*>(wsb + MFIB + (size_t)(tid + 256 * n) * 8);
        } else {
            ln_stage_raw<4>(su, 0, mps_out, tid);
        }
        BARRIER();
        float accl = 0.f;
        for (int i = 0; i < 256; i++) {
            int p = i & 1;
            int qw = (((i & 1) == 0) || i == 255) ? 4 : 2;
            float sc = 1.f;
            if (i > 0) {
                float* rb = red + (i & 1) * 8;
                float m4 = fmaxf(fmaxf(rb[0], rb[1]), fmaxf(rb[2], rb[3]));
                sc = 1.f / m4;
                if (tid == 0) accl += logf(m4);
            }
            if (qw == 4) ln_mm1<4>(su, p, p, sc, tid);
            else         ln_mm1<2>(su, p, p, sc, tid);
            if (i + 1 < 256) {
                int j = i + 1;
                int qn = (((j & 1) == 0) || j == 255) ? 4 : 2;
                if constexpr (BFS) {
#pragma unroll
                    for (int n = 0; n < 8; n++)
                        if (n < 2 * qn) {
                            int c = tid + 256 * n;
                            *reinterpret_cast<short8*>(su + L_MF(p ^ 1) + (c >> 3) * ST + (c & 7) * 8) = pf[n];
                        }
                } else {
                    if (qn == 4)
                        ln_stage_raw<4>(su, p ^ 1,
                                        mps_out + (size_t)16384 * ((j == 255) ? 128 : (j >> 1)), tid);
                    else
                        ln_stage_raw<2>(su, p ^ 1, mps_in + (size_t)8192 * (j >> 1), tid);
                }
            }
            if constexpr (BFS) {
                int j2 = i + 2;
                if (j2 < 256) {
                    int qn2 = (((j2 & 1) == 0) || j2 == 255) ? 4 : 2;
                    const ushort* src = (qn2 == 4)
                        ? wsb + MFOB + 16384ull * (unsigned)((j2 == 255) ? 128 : (j2 >> 1))
                        : wsb + MFIB + 8192ull * (unsigned)(j2 >> 1);
#pragma unroll
                    for (int n = 0; n < 8; n++)
                        if (n < 2 * qn2)
                            pf[n] = *reinterpret_cast<const short8*>(src + (size_t)(tid + 256 * n) * 8);
                }
            }
            if (qw == 4) ln_mm2<4>(su, p, p, tid, red + ((i + 1) & 1) * 8);
            else         ln_mm2<2>(su, p, p, tid, red + ((i + 1) & 1) * 8);
            BARRIER();
        }
        if (tid == 0) { accl += logf(b2f(su[L_AL(0)])); wsf[64] = accl; }
        return;
    }

    // ================= batched <psi|psi> chain (1 per block) =================
    const int b = blockIdx.x;
    float accl = 0.f;
    short8 pfA[4], pfX[8];

    auto loadpf = [&](int k2) {
        const ushort* mb = wsb + MINB + (size_t)(k2 - 1) * 8192;
        const ushort* xb = wsb + MOTB + (size_t)k2 * 16384;
#pragma unroll
        for (int n = 0; n < 4; n++)
            pfA[n] = *reinterpret_cast<const short8*>(mb + (size_t)(tid + 256 * n) * 8);
#pragma unroll
        for (int n = 0; n < 8; n++)
            pfX[n] = *reinterpret_cast<const short8*>(xb + (size_t)((n >> 2) * 1024 + tid + 256 * (n & 3)) * 8);
    };
    auto stage_bf = [&](int k2) {
        float jv0 = inp[((2 * k2 - 1) * 64 + b) * 2], jv1 = inp[((2 * k2 - 1) * 64 + b) * 2 + 1];
        float ov0 = inp[((2 * k2) * 64 + b) * 2],     ov1 = inp[((2 * k2) * 64 + b) * 2 + 1];
#pragma unroll
        for (int n = 0; n < 4; n++) {
            int c = tid + 256 * n, l = c >> 4, dd0 = (c & 15) * 4;
            short8 r8 = pfA[n];
            float v0 = jv0 * b2f((ushort)r8[0]) + jv1 * b2f((ushort)r8[1]);
            float v1 = jv0 * b2f((ushort)r8[2]) + jv1 * b2f((ushort)r8[3]);
            float v2 = jv0 * b2f((ushort)r8[4]) + jv1 * b2f((ushort)r8[5]);
            float v3 = jv0 * b2f((ushort)r8[6]) + jv1 * b2f((ushort)r8[7]);
            st64(&su[BPL(0) + l * ST + dd0], pk2(v0, v1), pk2(v2, v3));
        }
#pragma unroll
        for (int n = 0; n < 8; n++) {
            int j = n >> 2, c = tid + 256 * (n & 3), r = c >> 4, dd0 = (c & 15) * 4;
            short8 r8 = pfX[n];
            float v0 = ov0 * b2f((ushort)r8[0]) + ov1 * b2f((ushort)r8[1]);
            float v1 = ov0 * b2f((ushort)r8[2]) + ov1 * b2f((ushort)r8[3]);
            float v2 = ov0 * b2f((ushort)r8[4]) + ov1 * b2f((ushort)r8[5]);
            float v3 = ov0 * b2f((ushort)r8[6]) + ov1 * b2f((ushort)r8[7]);
            st64(&su[BPL(1 + j) + r * ST + dd0], pk2(v0, v1), pk2(v2, v3));
        }
    };
    auto stage_f32 = [&](int k2) {
        const int a63 = tid & 63, hi2 = tid >> 6;
        const float* Min = mps_in + (size_t)(k2 - 1) * 8192;
        const float* Mo  = mps_out + (size_t)k2 * 16384;
        float jv0 = inp[((2 * k2 - 1) * 64 + b) * 2], jv1 = inp[((2 * k2 - 1) * 64 + b) * 2 + 1];
        float ov0 = inp[((2 * k2) * 64 + b) * 2],     ov1 = inp[((2 * k2) * 64 + b) * 2 + 1];
#pragma unroll
        for (int n = 0; n < 8; n++) {
            int f = tid + 256 * n, l = f >> 5, dd = (2 * f) & 63;
            f32x4 v = *reinterpret_cast<const f32x4*>(Min + 4 * f);
            *reinterpret_cast<unsigned*>(&su[BPL(0) + l * ST + dd]) =
                pk2(jv0 * v[0] + jv1 * v[1], jv0 * v[2] + jv1 * v[3]);
        }
#pragma unroll
        for (int n = 0; n < 16; n++) {
            int r = hi2 + 4 * n;
            f32x4 v = *reinterpret_cast<const f32x4*>(Mo + 4 * ((size_t)a63 * 64 + r));
            su[BPL(1) + r * ST + a63] = f2b(ov0 * v[0] + ov1 * v[2]);
            su[BPL(2) + r * ST + a63] = f2b(ov0 * v[1] + ov1 * v[3]);
        }
    };

    if constexpr (BFS) loadpf(1);
    // ---- site 0 ----
    {
        float iv0 = inp[b * 2 + 0], iv1 = inp[b * 2 + 1];
        if (tid < 128) {
            int r = tid >> 1, jj = tid & 1;
            A0s[tid] = iv0 * mps_out[r * 4 + jj] + iv1 * mps_out[r * 4 + 2 + jj];
        }
        BARRIER();
        float vals[16];
        float lm = 0.f;
#pragma unroll
        for (int n = 0; n < 16; n++) {
            int e = tid + 256 * n;
            int u = e >> 6, d2 = e & 63;
            float v = A0s[2 * u] * A0s[2 * d2] + A0s[2 * u + 1] * A0s[2 * d2 + 1];
            vals[n] = v;
            lm = fmaxf(lm, fabsf(v));
        }
        float amax = blk_max(lm, bms, tid);
        if (tid == 0) accl += logf(amax);
        float sc0 = (amax > 0.f) ? 1.f / amax : 0.f;
#pragma unroll
        for (int n = 0; n < 16; n++) {
            int e = tid + 256 * n;
            su[BPL(7) + (e >> 6) * ST + (e & 63)] = f2b(vals[n] * sc0);
        }
    }
    if (tid < 4) red[4 + tid] = 1.0f;   // rb=1 slots for k=1
    if constexpr (BFS) {
        stage_bf(1);
        loadpf(2);
    } else {
        stage_f32(1);
    }
    BARRIER();

    for (int k = 1; k <= 127; k++) {
        int rb = k & 1;
        bt_mm1(su, tid);
        {
            float* r4 = red + rb * 4;
            float m4 = fmaxf(fmaxf(r4[0], r4[1]), fmaxf(r4[2], r4[3]));
            float sc = 1.f / m4;
            if (tid == 0) accl += logf(m4);
            bt_mm2(su, sc, tid);
        }
        BARRIER();  // B1: A_jT visible block-wide; T_j wave-local
        if (k < 127) {
            if constexpr (BFS) stage_bf(k + 1);
            else               stage_f32(k + 1);
        }
        bt_mm3(su, tid, red + (rb ^ 1) * 4);
        if constexpr (BFS) { if (k < 126) loadpf(k + 2); }
        BARRIER();  // B2: Al + staged site visible
    }

    // ---- final site i=255 ----
    {
        const float* Mo128 = mps_out + (size_t)128 * 16384;
        float fv0 = inp[(255 * 64 + b) * 2], fv1 = inp[(255 * 64 + b) * 2 + 1];
        if (tid < 128) {
            int d2 = tid >> 1, jj = tid & 1;
            A0s[tid] = fv0 * Mo128[d2 * 256 + jj] + fv1 * Mo128[d2 * 256 + 2 + jj];
        }
        BARRIER();
        float part = 0.f;
#pragma unroll
        for (int n = 0; n < 16; n++) {
            int e = tid + 256 * n;
            int d2 = e >> 6, u = e & 63;
            part += b2f(su[BPL(7) + d2 * ST + u]) *
                    (A0s[2 * d2] * A0s[2 * u] + A0s[2 * d2 + 1] * A0s[2 * u + 1]);
        }
#pragma unroll
        for (int off = 32; off > 0; off >>= 1)
            part += __shfl_xor(part, off, 64);
        BARRIER();
        if ((tid & 63) == 0) bms[tid >> 6] = part;
        BARRIER();
        if (tid == 0) {
            float v = bms[0] + bms[1] + bms[2] + bms[3];
            wsf[b] = accl + logf(fabsf(v));
        }
    }
}

__global__ void proj_combine(const float* __restrict__ ws, float* __restrict__ out, int n) {
    int t = threadIdx.x;
    if (t < n) out[t] = ws[t] - ws[64];
}

extern "C" void kernel_launch(void* const* d_in, const int* in_sizes, int n_in,
                              void* d_out, int out_size, void* d_ws, size_t ws_size,
                              hipStream_t stream) {
    const float* inp = (const float*)d_in[0];
    const float* mi  = (const float*)d_in[1];
    const float* mo  = (const float*)d_in[2];
    float* wsf = (float*)d_ws;
    ushort* wsb = (ushort*)((char*)d_ws + 512);
    size_t need = 512 + WS_U16_TOT * 2;
    if (ws_size >= need) {
        preconv<<<dim3(256), dim3(256), 0, stream>>>(mi, mo, wsb);
        proj_chain<true><<<dim3(65), dim3(256), 0, stream>>>(inp, mi, mo, wsf, wsb);
    } else {
        proj_chain<false><<<dim3(65), dim3(256), 0, stream>>>(inp, mi, mo, wsf, wsb);
    }
    proj_combine<<<dim3(1), dim3(64), 0, stream>>>(wsf, (float*)d_out, out_size);
}